// Round 6
// baseline (425.478 us; speedup 1.0000x reference)
//
#include <hip/hip_runtime.h>
#include <math.h>

#define NN 50000
#define NE 600000
#define D 128
#define NH 3
#define SCAN_BLOCKS ((NN + 255) / 256)   // 196

typedef short bf16x8 __attribute__((ext_vector_type(8)));
typedef float f32x4 __attribute__((ext_vector_type(4)));

__device__ __forceinline__ unsigned short f2b(float f) {
  unsigned int u = __float_as_uint(f);
  u += 0x7FFF + ((u >> 16) & 1);          // round-to-nearest-even
  return (unsigned short)(u >> 16);
}
__device__ __forceinline__ float b2f(unsigned short h) {
  return __uint_as_float((unsigned int)h << 16);
}

// ---------------------------------------------------------------------------
// GEMM (fp32, proven): used only for wcomb[h] = W_lin @ W_heads[h] (M=128).
// ---------------------------------------------------------------------------
__global__ __launch_bounds__(256) void gemm128(const float* __restrict__ X,
                                               const float* __restrict__ W,
                                               const float* __restrict__ bias,
                                               float* __restrict__ Y, int M,
                                               size_t wstride, size_t yoff,
                                               int pitch) {
  W += (size_t)blockIdx.y * wstride;
  Y += (size_t)blockIdx.y * yoff;
  __shared__ __align__(16) float xs[64][136];
  const int tid = threadIdx.x;
  const int row0 = blockIdx.x * 64;
  #pragma unroll
  for (int it = 0; it < 8; ++it) {
    int idx = tid + it * 256;
    int m = idx >> 5, k4 = idx & 31;
    float4 v = make_float4(0.f, 0.f, 0.f, 0.f);
    int row = row0 + m;
    if (row < M) v = ((const float4*)(X + (size_t)row * D))[k4];
    *((float4*)&xs[m][k4 * 4]) = v;
  }
  __syncthreads();
  const int tn = tid & 31;
  const int tm = tid >> 5;
  float acc[8][4];
  #pragma unroll
  for (int i = 0; i < 8; ++i)
    #pragma unroll
    for (int j = 0; j < 4; ++j) acc[i][j] = 0.f;

  for (int kb = 0; kb < 32; ++kb) {
    float4 b0 = ((const float4*)(W + (size_t)(kb * 4 + 0) * D))[tn];
    float4 b1 = ((const float4*)(W + (size_t)(kb * 4 + 1) * D))[tn];
    float4 b2 = ((const float4*)(W + (size_t)(kb * 4 + 2) * D))[tn];
    float4 b3 = ((const float4*)(W + (size_t)(kb * 4 + 3) * D))[tn];
    #pragma unroll
    for (int mi = 0; mi < 8; ++mi) {
      float4 a = *((const float4*)&xs[tm * 8 + mi][kb * 4]);
      acc[mi][0] += a.x * b0.x + a.y * b1.x + a.z * b2.x + a.w * b3.x;
      acc[mi][1] += a.x * b0.y + a.y * b1.y + a.z * b2.y + a.w * b3.y;
      acc[mi][2] += a.x * b0.z + a.y * b1.z + a.z * b2.z + a.w * b3.z;
      acc[mi][3] += a.x * b0.w + a.y * b1.w + a.z * b2.w + a.w * b3.w;
    }
  }
  float4 bv = make_float4(0.f, 0.f, 0.f, 0.f);
  if (bias) bv = ((const float4*)bias)[tn];
  #pragma unroll
  for (int mi = 0; mi < 8; ++mi) {
    int row = row0 + tm * 8 + mi;
    if (row < M) {
      float4 o;
      o.x = acc[mi][0] + bv.x;
      o.y = acc[mi][1] + bv.y;
      o.z = acc[mi][2] + bv.z;
      o.w = acc[mi][3] + bv.w;
      ((float4*)(Y + (size_t)row * pitch))[tn] = o;
    }
  }
}

// bcomb[h][n] = sum_k b_lin[k] * W_heads[h][k][n]
__global__ void prep_b(const float* __restrict__ b_lin,
                       const float* __restrict__ W_heads,
                       float* __restrict__ bcomb) {
  int t = blockIdx.x * 256 + threadIdx.x;
  if (t >= NH * D) return;
  int h = t / D, n = t - h * D;
  float acc = 0.f;
  for (int k = 0; k < D; ++k) acc += b_lin[k] * W_heads[h * D * D + k * D + n];
  bcomb[t] = acc;
}

// ---------------------------------------------------------------------------
// Reorder wcomb (fp32 [h][k][n]) into bf16 MFMA B-fragment order (proven r5).
// ---------------------------------------------------------------------------
__global__ void pack_b(const float* __restrict__ wcomb, uint4* __restrict__ Bpack) {
  int u = blockIdx.x * 256 + threadIdx.x;
  if (u >= NH * 2048) return;
  int h = u >> 11, r = u & 2047;
  int nt = r >> 8, s = (r >> 6) & 3, q = (r >> 4) & 3, n0 = r & 15;
  const float* W = wcomb + h * D * D + (s * 32 + q * 8) * D + nt * 16 + n0;
  unsigned int w[4];
  #pragma unroll
  for (int p = 0; p < 4; ++p) {
    unsigned int lo = f2b(W[(2 * p) * D]);
    unsigned int hi = f2b(W[(2 * p + 1) * D]);
    w[p] = lo | (hi << 16);
  }
  Bpack[u] = make_uint4(w[0], w[1], w[2], w[3]);
}

// ---------------------------------------------------------------------------
// Fused: h3 (bf16, all 3 heads, x staged once) + s_src/s_dst scores.
// ---------------------------------------------------------------------------
__global__ __launch_bounds__(256) void mfma_h3f(const float* __restrict__ x,
                                                const uint4* __restrict__ Bpack,
                                                const float* __restrict__ bcomb,
                                                const float* __restrict__ att_src,
                                                const float* __restrict__ att_dst,
                                                unsigned short* __restrict__ h3,
                                                float* __restrict__ s_src,
                                                float* __restrict__ s_dst) {
  const int row0 = blockIdx.x * 64;
  __shared__ __align__(16) unsigned short As[64][136];
  const int tid = threadIdx.x;
  #pragma unroll
  for (int it = 0; it < 8; ++it) {
    int idx = tid + it * 256;
    int m = idx >> 5, k4 = idx & 31;
    int row = row0 + m;
    float4 v = make_float4(0.f, 0.f, 0.f, 0.f);
    if (row < NN) v = ((const float4*)(x + (size_t)row * D))[k4];
    uint2 pk;
    pk.x = (unsigned int)f2b(v.x) | ((unsigned int)f2b(v.y) << 16);
    pk.y = (unsigned int)f2b(v.z) | ((unsigned int)f2b(v.w) << 16);
    *((uint2*)&As[m][k4 * 4]) = pk;
  }
  __syncthreads();
  const int wv = tid >> 6;
  const int lane = tid & 63;
  const int n0 = lane & 15, q = lane >> 4;

  f32x4 acc[NH][8];
  #pragma unroll
  for (int hd = 0; hd < NH; ++hd)
    #pragma unroll
    for (int nt = 0; nt < 8; ++nt) acc[hd][nt] = (f32x4){0.f, 0.f, 0.f, 0.f};

  #pragma unroll
  for (int s = 0; s < 4; ++s) {
    bf16x8 a = *(const bf16x8*)&As[wv * 16 + n0][s * 32 + q * 8];
    #pragma unroll
    for (int hd = 0; hd < NH; ++hd) {
      #pragma unroll
      for (int nt = 0; nt < 8; ++nt) {
        bf16x8 b = *(const bf16x8*)&Bpack[hd * 2048 + nt * 256 + s * 64 + q * 16 + n0];
        acc[hd][nt] = __builtin_amdgcn_mfma_f32_16x16x32_bf16(a, b, acc[hd][nt], 0, 0, 0);
      }
    }
  }

  float ss[NH][4], sd[NH][4];
  #pragma unroll
  for (int hd = 0; hd < NH; ++hd)
    #pragma unroll
    for (int r = 0; r < 4; ++r) { ss[hd][r] = 0.f; sd[hd][r] = 0.f; }

  #pragma unroll
  for (int hd = 0; hd < NH; ++hd) {
    #pragma unroll
    for (int nt = 0; nt < 8; ++nt) {
      int col = nt * 16 + n0;
      float bv = bcomb[hd * D + col];
      float va = att_src[hd * D + col];
      float vd = att_dst[hd * D + col];
      #pragma unroll
      for (int r = 0; r < 4; ++r) {
        float hv = acc[hd][nt][r] + bv;
        int row = row0 + wv * 16 + q * 4 + r;
        if (row < NN) h3[(size_t)row * (NH * D) + hd * D + col] = f2b(hv);
        ss[hd][r] += hv * va;
        sd[hd][r] += hv * vd;
      }
    }
  }
  #pragma unroll
  for (int hd = 0; hd < NH; ++hd) {
    #pragma unroll
    for (int r = 0; r < 4; ++r) {
      float v1 = ss[hd][r], v2 = sd[hd][r];
      #pragma unroll
      for (int m = 1; m < 16; m <<= 1) {
        v1 += __shfl_xor(v1, m, 64);
        v2 += __shfl_xor(v2, m, 64);
      }
      int row = row0 + wv * 16 + q * 4 + r;
      if (n0 == hd * 4 + r && row < NN) {
        s_src[row * NH + hd] = v1;
        s_dst[row * NH + hd] = v2;
      }
    }
  }
}

// --------------------------- CSR build (proven) ----------------------------
__global__ void zero_counts(int* __restrict__ counts) {
  int i = blockIdx.x * 256 + threadIdx.x;
  if (i < NN) counts[i] = 0;
}

__global__ void histogram(const int* __restrict__ ei, int* __restrict__ counts) {
  int e = blockIdx.x * 256 + threadIdx.x;
  if (e < NE) atomicAdd(&counts[ei[NE + e]], 1);
}

__global__ __launch_bounds__(256) void scan1(const int* __restrict__ counts,
                                             int* __restrict__ expart,
                                             int* __restrict__ blocksums) {
  __shared__ int tmp[2][256];
  int i = blockIdx.x * 256 + threadIdx.x;
  int t = threadIdx.x;
  int v = (i < NN) ? counts[i] : 0;
  tmp[0][t] = v;
  __syncthreads();
  int cur = 0;
  #pragma unroll
  for (int off = 1; off < 256; off <<= 1) {
    int nv = tmp[cur][t] + (t >= off ? tmp[cur][t - off] : 0);
    tmp[1 - cur][t] = nv;
    cur = 1 - cur;
    __syncthreads();
  }
  if (i < NN) expart[i] = tmp[cur][t] - v;
  if (t == 255) blocksums[blockIdx.x] = tmp[cur][t];
}

__global__ __launch_bounds__(256) void scan2(int* __restrict__ blocksums) {
  __shared__ int tmp[2][256];
  int t = threadIdx.x;
  int v = (t < SCAN_BLOCKS) ? blocksums[t] : 0;
  tmp[0][t] = v;
  __syncthreads();
  int cur = 0;
  #pragma unroll
  for (int off = 1; off < 256; off <<= 1) {
    int nv = tmp[cur][t] + (t >= off ? tmp[cur][t - off] : 0);
    tmp[1 - cur][t] = nv;
    cur = 1 - cur;
    __syncthreads();
  }
  if (t < SCAN_BLOCKS) blocksums[t] = tmp[cur][t] - v;
}

__global__ void scan3(const int* __restrict__ expart, const int* __restrict__ blocksums,
                      int* __restrict__ row_start, int* __restrict__ cursor) {
  int i = blockIdx.x * 256 + threadIdx.x;
  if (i < NN) {
    int v = expart[i] + blocksums[blockIdx.x];
    row_start[i] = v;
    cursor[i] = v;
  }
  if (i == 0) row_start[NN] = NE;
}

// ---------------------------------------------------------------------------
// Scatter edges into CSR slots; slots[slot] = {bitcast(src), p0, p1, p2}.
// ---------------------------------------------------------------------------
__global__ __launch_bounds__(256) void scatter(const int* __restrict__ ei,
                                               const int* __restrict__ eid,
                                               const float* __restrict__ ddi,
                                               const float* __restrict__ emb,
                                               const float* __restrict__ s_src,
                                               const float* __restrict__ s_dst,
                                               int* __restrict__ cursor,
                                               float4* __restrict__ slots,
                                               float* __restrict__ ews) {
  int e = blockIdx.x * 256 + threadIdx.x;
  if (e >= NE) return;
  int src = ei[e], dst = ei[NE + e];
  int slot = atomicAdd(&cursor[dst], 1);
  float p[NH];
  #pragma unroll
  for (int hd = 0; hd < NH; ++hd) {
    float v = s_src[src * NH + hd] + s_dst[dst * NH + hd];
    v = v > 0.f ? v : 0.2f * v;
    p[hd] = __expf(v);
  }
  slots[slot] = make_float4(__int_as_float(src), p[0], p[1], p[2]);
  ews[slot] = emb[eid[e]] - ddi[e];
}

// ---------------------------------------------------------------------------
// Gather v3: one wave per (dst, head); block 384 = 2 dst x 3 head-waves.
// 2-edge unroll for ILP. Per-head results combined through LDS; out written
// exactly once, no atomics. denominator = sum p (wave-uniform).
// ---------------------------------------------------------------------------
__global__ __launch_bounds__(384) void gather3(const int* __restrict__ row_start,
                                               const float4* __restrict__ slots,
                                               const float* __restrict__ ews,
                                               const unsigned short* __restrict__ h3,
                                               const float* __restrict__ bias_heads,
                                               float* __restrict__ out) {
  __shared__ float sm[2][NH][D];
  const int local = threadIdx.x / 192;     // which of the 2 dst
  const int r = threadIdx.x % 192;
  const int head = r >> 6;                 // wave-uniform
  const int lane = r & 63;
  const int dst = blockIdx.x * 2 + local;
  const int c = lane * 2;
  const int beg = row_start[dst], end = row_start[dst + 1];
  float na = 0.f, nb = 0.f, den = 0.f;
  int s = beg;
  for (; s + 1 < end; s += 2) {
    float4 sl0 = slots[s], sl1 = slots[s + 1];
    float ew0 = ews[s], ew1 = ews[s + 1];
    int src0 = __float_as_int(sl0.x), src1 = __float_as_int(sl1.x);
    float p0 = head == 0 ? sl0.y : (head == 1 ? sl0.z : sl0.w);
    float p1 = head == 0 ? sl1.y : (head == 1 ? sl1.z : sl1.w);
    unsigned int u0 = *(const unsigned int*)&h3[(size_t)src0 * (NH * D) + head * D + c];
    unsigned int u1 = *(const unsigned int*)&h3[(size_t)src1 * (NH * D) + head * D + c];
    float w0 = p0 * ew0, w1 = p1 * ew1;
    na += w0 * __uint_as_float(u0 << 16) + w1 * __uint_as_float(u1 << 16);
    nb += w0 * __uint_as_float(u0 & 0xffff0000u) + w1 * __uint_as_float(u1 & 0xffff0000u);
    den += p0 + p1;
  }
  if (s < end) {
    float4 sl0 = slots[s];
    float ew0 = ews[s];
    int src0 = __float_as_int(sl0.x);
    float p0 = head == 0 ? sl0.y : (head == 1 ? sl0.z : sl0.w);
    unsigned int u0 = *(const unsigned int*)&h3[(size_t)src0 * (NH * D) + head * D + c];
    float w0 = p0 * ew0;
    na += w0 * __uint_as_float(u0 << 16);
    nb += w0 * __uint_as_float(u0 & 0xffff0000u);
    den += p0;
  }
  float rd = 1.f / fmaxf(den, 1e-16f);
  *((float2*)&sm[local][head][c]) = make_float2(na * rd, nb * rd);
  __syncthreads();
  if (r < D) {
    float o = sm[local][0][r] + sm[local][1][r] + sm[local][2][r] +
              bias_heads[r] + bias_heads[D + r] + bias_heads[2 * D + r];
    out[(size_t)dst * D + r] = o * (1.f / 3.f);
  }
}

// ---------------------------------------------------------------------------
extern "C" void kernel_launch(void* const* d_in, const int* in_sizes, int n_in,
                              void* d_out, int out_size, void* d_ws, size_t ws_size,
                              hipStream_t stream) {
  const float* x          = (const float*)d_in[0];
  const int*   ei         = (const int*)d_in[1];
  const int*   eid        = (const int*)d_in[2];
  const float* ddi        = (const float*)d_in[3];
  const float* W_lin      = (const float*)d_in[4];
  const float* b_lin      = (const float*)d_in[5];
  const float* emb        = (const float*)d_in[6];
  const float* W_heads    = (const float*)d_in[7];
  const float* att_src    = (const float*)d_in[8];
  const float* att_dst    = (const float*)d_in[9];
  const float* bias_heads = (const float*)d_in[10];
  float* out = (float*)d_out;

  // workspace layout (16B-aligned chunks first)
  float4* slots  = (float4*)d_ws;                              // NE
  uint4*  Bpack  = (uint4*)(slots + NE);                       // NH*2048
  unsigned short* h3 = (unsigned short*)(Bpack + NH * 2048);   // NN*NH*D bf16
  float*  wcomb  = (float*)(h3 + (size_t)NN * NH * D);         // NH*D*D
  float*  ews    = wcomb + NH * D * D;                         // NE
  float*  bcomb  = ews + NE;                                   // NH*D
  float*  s_src  = bcomb + NH * D;                             // NN*NH
  float*  s_dst  = s_src + NN * NH;                            // NN*NH
  int*    counts = (int*)(s_dst + NN * NH);                    // NN
  int*    expart = counts + NN;                                // NN
  int*    bsums  = expart + NN;                                // 256
  int*    rstart = bsums + 256;                                // NN+1
  int*    cursor = rstart + NN + 1;                            // NN

  const int edgeBlocks = (NE + 255) / 256;
  const int nodeBlocks = (NN + 255) / 256;

  // 1. wcomb[h] = W_lin @ W_heads[h]
  gemm128<<<dim3(2, NH), 256, 0, stream>>>(W_lin, W_heads, nullptr, wcomb, D,
                                           (size_t)D * D, (size_t)D * D, D);
  // 2. bcomb[h] = b_lin @ W_heads[h]
  prep_b<<<(NH * D + 255) / 256, 256, 0, stream>>>(b_lin, W_heads, bcomb);
  // 3. Bpack = bf16 fragment-ordered wcomb
  pack_b<<<(NH * 2048 + 255) / 256, 256, 0, stream>>>(wcomb, Bpack);
  // 4. h3 (all heads) + attention scores, fused
  mfma_h3f<<<(NN + 63) / 64, 256, 0, stream>>>(x, Bpack, bcomb, att_src, att_dst,
                                               h3, s_src, s_dst);
  // 5. CSR build
  zero_counts<<<nodeBlocks, 256, 0, stream>>>(counts);
  histogram<<<edgeBlocks, 256, 0, stream>>>(ei, counts);
  scan1<<<SCAN_BLOCKS, 256, 0, stream>>>(counts, expart, bsums);
  scan2<<<1, 256, 0, stream>>>(bsums);
  scan3<<<SCAN_BLOCKS, 256, 0, stream>>>(expart, bsums, rstart, cursor);
  // 6. scatter edges into CSR + precompute p, ew
  scatter<<<edgeBlocks, 256, 0, stream>>>(ei, eid, ddi, emb, s_src, s_dst, cursor,
                                          slots, ews);
  // 7. per-(dst,head) gather + LDS combine (no atomics)
  gather3<<<NN / 2, 384, 0, stream>>>(rstart, slots, ews, h3, bias_heads, out);
}

// Round 7
// 399.317 us; speedup vs baseline: 1.0655x; 1.0655x over previous
//
#include <hip/hip_runtime.h>
#include <math.h>

#define NN 50000
#define NE 600000
#define D 128
#define NH 3
#define SCAN_BLOCKS ((NN + 255) / 256)   // 196

typedef short bf16x8 __attribute__((ext_vector_type(8)));
typedef float f32x4 __attribute__((ext_vector_type(4)));

__device__ __forceinline__ unsigned short f2b(float f) {
  unsigned int u = __float_as_uint(f);
  u += 0x7FFF + ((u >> 16) & 1);          // round-to-nearest-even
  return (unsigned short)(u >> 16);
}
__device__ __forceinline__ float b2f(unsigned short h) {
  return __uint_as_float((unsigned int)h << 16);
}
__device__ __forceinline__ float blo(unsigned int u) {
  return __uint_as_float(u << 16);
}
__device__ __forceinline__ float bhi(unsigned int u) {
  return __uint_as_float(u & 0xffff0000u);
}

// ---------------------------------------------------------------------------
// GEMM (fp32, proven): used only for wcomb[h] = W_lin @ W_heads[h] (M=128).
// ---------------------------------------------------------------------------
__global__ __launch_bounds__(256) void gemm128(const float* __restrict__ X,
                                               const float* __restrict__ W,
                                               const float* __restrict__ bias,
                                               float* __restrict__ Y, int M,
                                               size_t wstride, size_t yoff,
                                               int pitch) {
  W += (size_t)blockIdx.y * wstride;
  Y += (size_t)blockIdx.y * yoff;
  __shared__ __align__(16) float xs[64][136];
  const int tid = threadIdx.x;
  const int row0 = blockIdx.x * 64;
  #pragma unroll
  for (int it = 0; it < 8; ++it) {
    int idx = tid + it * 256;
    int m = idx >> 5, k4 = idx & 31;
    float4 v = make_float4(0.f, 0.f, 0.f, 0.f);
    int row = row0 + m;
    if (row < M) v = ((const float4*)(X + (size_t)row * D))[k4];
    *((float4*)&xs[m][k4 * 4]) = v;
  }
  __syncthreads();
  const int tn = tid & 31;
  const int tm = tid >> 5;
  float acc[8][4];
  #pragma unroll
  for (int i = 0; i < 8; ++i)
    #pragma unroll
    for (int j = 0; j < 4; ++j) acc[i][j] = 0.f;

  for (int kb = 0; kb < 32; ++kb) {
    float4 b0 = ((const float4*)(W + (size_t)(kb * 4 + 0) * D))[tn];
    float4 b1 = ((const float4*)(W + (size_t)(kb * 4 + 1) * D))[tn];
    float4 b2 = ((const float4*)(W + (size_t)(kb * 4 + 2) * D))[tn];
    float4 b3 = ((const float4*)(W + (size_t)(kb * 4 + 3) * D))[tn];
    #pragma unroll
    for (int mi = 0; mi < 8; ++mi) {
      float4 a = *((const float4*)&xs[tm * 8 + mi][kb * 4]);
      acc[mi][0] += a.x * b0.x + a.y * b1.x + a.z * b2.x + a.w * b3.x;
      acc[mi][1] += a.x * b0.y + a.y * b1.y + a.z * b2.y + a.w * b3.y;
      acc[mi][2] += a.x * b0.z + a.y * b1.z + a.z * b2.z + a.w * b3.z;
      acc[mi][3] += a.x * b0.w + a.y * b1.w + a.z * b2.w + a.w * b3.w;
    }
  }
  float4 bv = make_float4(0.f, 0.f, 0.f, 0.f);
  if (bias) bv = ((const float4*)bias)[tn];
  #pragma unroll
  for (int mi = 0; mi < 8; ++mi) {
    int row = row0 + tm * 8 + mi;
    if (row < M) {
      float4 o;
      o.x = acc[mi][0] + bv.x;
      o.y = acc[mi][1] + bv.y;
      o.z = acc[mi][2] + bv.z;
      o.w = acc[mi][3] + bv.w;
      ((float4*)(Y + (size_t)row * pitch))[tn] = o;
    }
  }
}

// bcomb[h][n] = sum_k b_lin[k] * W_heads[h][k][n]
__global__ void prep_b(const float* __restrict__ b_lin,
                       const float* __restrict__ W_heads,
                       float* __restrict__ bcomb) {
  int t = blockIdx.x * 256 + threadIdx.x;
  if (t >= NH * D) return;
  int h = t / D, n = t - h * D;
  float acc = 0.f;
  for (int k = 0; k < D; ++k) acc += b_lin[k] * W_heads[h * D * D + k * D + n];
  bcomb[t] = acc;
}

// ---------------------------------------------------------------------------
// Reorder wcomb (fp32 [h][k][n]) into bf16 MFMA B-fragment order (proven r5).
// ---------------------------------------------------------------------------
__global__ void pack_b(const float* __restrict__ wcomb, uint4* __restrict__ Bpack) {
  int u = blockIdx.x * 256 + threadIdx.x;
  if (u >= NH * 2048) return;
  int h = u >> 11, r = u & 2047;
  int nt = r >> 8, s = (r >> 6) & 3, q = (r >> 4) & 3, n0 = r & 15;
  const float* W = wcomb + h * D * D + (s * 32 + q * 8) * D + nt * 16 + n0;
  unsigned int w[4];
  #pragma unroll
  for (int p = 0; p < 4; ++p) {
    unsigned int lo = f2b(W[(2 * p) * D]);
    unsigned int hi = f2b(W[(2 * p + 1) * D]);
    w[p] = lo | (hi << 16);
  }
  Bpack[u] = make_uint4(w[0], w[1], w[2], w[3]);
}

// ---------------------------------------------------------------------------
// h3[n][head][d] (bf16) = x @ wcomb[head] + bcomb[head], via MFMA 16x16x32.
// (round-5 proven version, one head per grid.y)
// ---------------------------------------------------------------------------
__global__ __launch_bounds__(256) void mfma_h3(const float* __restrict__ x,
                                               const uint4* __restrict__ Bpack,
                                               const float* __restrict__ bcomb,
                                               unsigned short* __restrict__ h3) {
  const int head = blockIdx.y;
  const int row0 = blockIdx.x * 64;
  __shared__ __align__(16) unsigned short As[64][136];
  const int tid = threadIdx.x;
  #pragma unroll
  for (int it = 0; it < 8; ++it) {
    int idx = tid + it * 256;
    int m = idx >> 5, k4 = idx & 31;
    int row = row0 + m;
    float4 v = make_float4(0.f, 0.f, 0.f, 0.f);
    if (row < NN) v = ((const float4*)(x + (size_t)row * D))[k4];
    uint2 pk;
    pk.x = (unsigned int)f2b(v.x) | ((unsigned int)f2b(v.y) << 16);
    pk.y = (unsigned int)f2b(v.z) | ((unsigned int)f2b(v.w) << 16);
    *((uint2*)&As[m][k4 * 4]) = pk;
  }
  __syncthreads();
  const int wv = tid >> 6;
  const int lane = tid & 63;
  const int n0 = lane & 15, q = lane >> 4;
  const bf16x8* Bp = (const bf16x8*)(Bpack + head * 2048);

  f32x4 acc[8];
  #pragma unroll
  for (int nt = 0; nt < 8; ++nt) acc[nt] = (f32x4){0.f, 0.f, 0.f, 0.f};

  #pragma unroll
  for (int s = 0; s < 4; ++s) {
    bf16x8 a = *(const bf16x8*)&As[wv * 16 + n0][s * 32 + q * 8];
    #pragma unroll
    for (int nt = 0; nt < 8; ++nt) {
      bf16x8 b = Bp[(nt * 4 + s) * 64 + q * 16 + n0];
      acc[nt] = __builtin_amdgcn_mfma_f32_16x16x32_bf16(a, b, acc[nt], 0, 0, 0);
    }
  }
  const float* bc = bcomb + head * D;
  unsigned short* H = h3 + (size_t)head * D;
  #pragma unroll
  for (int nt = 0; nt < 8; ++nt) {
    int col = nt * 16 + n0;
    float bv = bc[col];
    #pragma unroll
    for (int r = 0; r < 4; ++r) {
      int row = row0 + wv * 16 + q * 4 + r;
      if (row < NN) H[(size_t)row * (NH * D) + col] = f2b(acc[nt][r] + bv);
    }
  }
}

// ---------------------------------------------------------------------------
// s_src[n*3+h] = h3[n][h] . att_src[h];  s_dst likewise. One wave per (n,h).
// (round-5 proven version)
// ---------------------------------------------------------------------------
__global__ __launch_bounds__(256) void score_kernel(const unsigned short* __restrict__ h3,
                                                    const float* __restrict__ att_src,
                                                    const float* __restrict__ att_dst,
                                                    float* __restrict__ s_src,
                                                    float* __restrict__ s_dst) {
  int wave = (blockIdx.x * 256 + threadIdx.x) >> 6;
  int lane = threadIdx.x & 63;
  if (wave >= NN * NH) return;
  int n = wave / NH;
  int hd = wave - n * NH;
  const unsigned short* hp = h3 + ((size_t)n * NH + hd) * D;
  float v1 = b2f(hp[lane]), v2 = b2f(hp[lane + 64]);
  float as = att_src[hd * D + lane] * v1 + att_src[hd * D + lane + 64] * v2;
  float ad = att_dst[hd * D + lane] * v1 + att_dst[hd * D + lane + 64] * v2;
  #pragma unroll
  for (int off = 32; off > 0; off >>= 1) {
    as += __shfl_down(as, off, 64);
    ad += __shfl_down(ad, off, 64);
  }
  if (lane == 0) {
    s_src[n * NH + hd] = as;
    s_dst[n * NH + hd] = ad;
  }
}

// --------------------------- CSR build (proven) ----------------------------
__global__ void histogram(const int* __restrict__ ei, int* __restrict__ counts) {
  int e = blockIdx.x * 256 + threadIdx.x;
  if (e < NE) atomicAdd(&counts[ei[NE + e]], 1);
}

__global__ __launch_bounds__(256) void scan1(const int* __restrict__ counts,
                                             int* __restrict__ expart,
                                             int* __restrict__ blocksums) {
  __shared__ int tmp[2][256];
  int i = blockIdx.x * 256 + threadIdx.x;
  int t = threadIdx.x;
  int v = (i < NN) ? counts[i] : 0;
  tmp[0][t] = v;
  __syncthreads();
  int cur = 0;
  #pragma unroll
  for (int off = 1; off < 256; off <<= 1) {
    int nv = tmp[cur][t] + (t >= off ? tmp[cur][t - off] : 0);
    tmp[1 - cur][t] = nv;
    cur = 1 - cur;
    __syncthreads();
  }
  if (i < NN) expart[i] = tmp[cur][t] - v;
  if (t == 255) blocksums[blockIdx.x] = tmp[cur][t];
}

__global__ __launch_bounds__(256) void scan2(int* __restrict__ blocksums) {
  __shared__ int tmp[2][256];
  int t = threadIdx.x;
  int v = (t < SCAN_BLOCKS) ? blocksums[t] : 0;
  tmp[0][t] = v;
  __syncthreads();
  int cur = 0;
  #pragma unroll
  for (int off = 1; off < 256; off <<= 1) {
    int nv = tmp[cur][t] + (t >= off ? tmp[cur][t - off] : 0);
    tmp[1 - cur][t] = nv;
    cur = 1 - cur;
    __syncthreads();
  }
  if (t < SCAN_BLOCKS) blocksums[t] = tmp[cur][t] - v;
}

__global__ void scan3(const int* __restrict__ expart, const int* __restrict__ blocksums,
                      int* __restrict__ row_start, int* __restrict__ cursor) {
  int i = blockIdx.x * 256 + threadIdx.x;
  if (i < NN) {
    int v = expart[i] + blocksums[blockIdx.x];
    row_start[i] = v;
    cursor[i] = v;
  }
  if (i == 0) row_start[NN] = NE;
}

// ---------------------------------------------------------------------------
// Scatter v2: slots[slot] = {bitcast(src), p0*ew, p1*ew, p2*ew}; also
// accumulates denom[dst*3+h] += p_h via atomics (removes per-edge den work
// and the ews stream from the gather hot loop).
// ---------------------------------------------------------------------------
__global__ __launch_bounds__(256) void scatter2(const int* __restrict__ ei,
                                                const int* __restrict__ eid,
                                                const float* __restrict__ ddi,
                                                const float* __restrict__ emb,
                                                const float* __restrict__ s_src,
                                                const float* __restrict__ s_dst,
                                                int* __restrict__ cursor,
                                                float* __restrict__ denom,
                                                float4* __restrict__ slots) {
  int e = blockIdx.x * 256 + threadIdx.x;
  if (e >= NE) return;
  int src = ei[e], dst = ei[NE + e];
  int slot = atomicAdd(&cursor[dst], 1);
  float ew = emb[eid[e]] - ddi[e];
  float p[NH];
  #pragma unroll
  for (int hd = 0; hd < NH; ++hd) {
    float v = s_src[src * NH + hd] + s_dst[dst * NH + hd];
    v = v > 0.f ? v : 0.2f * v;
    p[hd] = __expf(v);   // no max-subtraction: |v| <= ~10, exp safe in fp32
    atomicAdd(&denom[dst * NH + hd], p[hd]);
  }
  slots[slot] = make_float4(__int_as_float(src), p[0] * ew, p[1] * ew, p[2] * ew);
}

// ---------------------------------------------------------------------------
// Gather v4: one dst per 128-thr block; 2 waves split the CSR row into halves
// (no redundant per-edge work), 2-edge unroll inside each wave. Denominators
// read once per dst from global. LDS combine (1.5 KB), out written once.
// ---------------------------------------------------------------------------
__global__ __launch_bounds__(128) void gather4(const int* __restrict__ row_start,
                                               const float4* __restrict__ slots,
                                               const unsigned short* __restrict__ h3,
                                               const float* __restrict__ denom,
                                               const float* __restrict__ bias_heads,
                                               float* __restrict__ out) {
  __shared__ float sm[6][64];
  const int dst = blockIdx.x;
  const int wv = threadIdx.x >> 6;
  const int lane = threadIdx.x & 63;
  const int c = lane * 2;
  const int beg = row_start[dst], end = row_start[dst + 1];
  const int mid = (beg + end) >> 1;
  int s = wv ? mid : beg;
  const int s1 = wv ? end : mid;
  float a00 = 0.f, a01 = 0.f, a10 = 0.f, a11 = 0.f, a20 = 0.f, a21 = 0.f;
  for (; s + 1 < s1; s += 2) {
    float4 A = slots[s], B = slots[s + 1];
    const unsigned short* ha = h3 + (size_t)__float_as_int(A.x) * (NH * D);
    const unsigned short* hb = h3 + (size_t)__float_as_int(B.x) * (NH * D);
    unsigned int ua0 = *(const unsigned int*)&ha[c];
    unsigned int ua1 = *(const unsigned int*)&ha[D + c];
    unsigned int ua2 = *(const unsigned int*)&ha[2 * D + c];
    unsigned int ub0 = *(const unsigned int*)&hb[c];
    unsigned int ub1 = *(const unsigned int*)&hb[D + c];
    unsigned int ub2 = *(const unsigned int*)&hb[2 * D + c];
    a00 += A.y * blo(ua0) + B.y * blo(ub0);
    a01 += A.y * bhi(ua0) + B.y * bhi(ub0);
    a10 += A.z * blo(ua1) + B.z * blo(ub1);
    a11 += A.z * bhi(ua1) + B.z * bhi(ub1);
    a20 += A.w * blo(ua2) + B.w * blo(ub2);
    a21 += A.w * bhi(ua2) + B.w * bhi(ub2);
  }
  if (s < s1) {
    float4 A = slots[s];
    const unsigned short* ha = h3 + (size_t)__float_as_int(A.x) * (NH * D);
    unsigned int ua0 = *(const unsigned int*)&ha[c];
    unsigned int ua1 = *(const unsigned int*)&ha[D + c];
    unsigned int ua2 = *(const unsigned int*)&ha[2 * D + c];
    a00 += A.y * blo(ua0);
    a01 += A.y * bhi(ua0);
    a10 += A.z * blo(ua1);
    a11 += A.z * bhi(ua1);
    a20 += A.w * blo(ua2);
    a21 += A.w * bhi(ua2);
  }
  if (wv == 1) {
    sm[0][lane] = a00; sm[1][lane] = a01;
    sm[2][lane] = a10; sm[3][lane] = a11;
    sm[4][lane] = a20; sm[5][lane] = a21;
  }
  __syncthreads();
  if (wv == 0) {
    a00 += sm[0][lane]; a01 += sm[1][lane];
    a10 += sm[2][lane]; a11 += sm[3][lane];
    a20 += sm[4][lane]; a21 += sm[5][lane];
    float r0 = 1.f / fmaxf(denom[dst * NH + 0], 1e-16f);
    float r1 = 1.f / fmaxf(denom[dst * NH + 1], 1e-16f);
    float r2 = 1.f / fmaxf(denom[dst * NH + 2], 1e-16f);
    float o0 = a00 * r0 + a10 * r1 + a20 * r2 +
               bias_heads[c] + bias_heads[D + c] + bias_heads[2 * D + c];
    float o1 = a01 * r0 + a11 * r1 + a21 * r2 +
               bias_heads[c + 1] + bias_heads[D + c + 1] + bias_heads[2 * D + c + 1];
    *((float2*)&out[(size_t)dst * D + c]) = make_float2(o0 * (1.f / 3.f),
                                                        o1 * (1.f / 3.f));
  }
}

// ---------------------------------------------------------------------------
extern "C" void kernel_launch(void* const* d_in, const int* in_sizes, int n_in,
                              void* d_out, int out_size, void* d_ws, size_t ws_size,
                              hipStream_t stream) {
  const float* x          = (const float*)d_in[0];
  const int*   ei         = (const int*)d_in[1];
  const int*   eid        = (const int*)d_in[2];
  const float* ddi        = (const float*)d_in[3];
  const float* W_lin      = (const float*)d_in[4];
  const float* b_lin      = (const float*)d_in[5];
  const float* emb        = (const float*)d_in[6];
  const float* W_heads    = (const float*)d_in[7];
  const float* att_src    = (const float*)d_in[8];
  const float* att_dst    = (const float*)d_in[9];
  const float* bias_heads = (const float*)d_in[10];
  float* out = (float*)d_out;

  // workspace layout (16B-aligned chunks first)
  float4* slots  = (float4*)d_ws;                              // NE
  uint4*  Bpack  = (uint4*)(slots + NE);                       // NH*2048
  unsigned short* h3 = (unsigned short*)(Bpack + NH * 2048);   // NN*NH*D bf16
  float*  wcomb  = (float*)(h3 + (size_t)NN * NH * D);         // NH*D*D
  float*  bcomb  = wcomb + NH * D * D;                         // NH*D
  float*  s_src  = bcomb + NH * D;                             // NN*NH
  float*  s_dst  = s_src + NN * NH;                            // NN*NH
  float*  denom  = s_dst + NN * NH;                            // NN*NH   (zeroed)
  int*    counts = (int*)(denom + NN * NH);                    // NN      (zeroed)
  int*    expart = counts + NN;                                // NN
  int*    bsums  = expart + NN;                                // 256
  int*    rstart = bsums + 256;                                // NN+1
  int*    cursor = rstart + NN + 1;                            // NN

  const int edgeBlocks = (NE + 255) / 256;

  // 0. zero denom + counts in one memset (they are contiguous)
  hipMemsetAsync(denom, 0, (size_t)(NN * NH + NN) * sizeof(float), stream);
  // 1. wcomb[h] = W_lin @ W_heads[h]
  gemm128<<<dim3(2, NH), 256, 0, stream>>>(W_lin, W_heads, nullptr, wcomb, D,
                                           (size_t)D * D, (size_t)D * D, D);
  // 2. bcomb[h] = b_lin @ W_heads[h]
  prep_b<<<(NH * D + 255) / 256, 256, 0, stream>>>(b_lin, W_heads, bcomb);
  // 3. Bpack = bf16 fragment-ordered wcomb
  pack_b<<<(NH * 2048 + 255) / 256, 256, 0, stream>>>(wcomb, Bpack);
  // 4. h3 = x @ wcomb + bcomb   (MFMA bf16, round-5 proven)
  mfma_h3<<<dim3((NN + 63) / 64, NH), 256, 0, stream>>>(x, Bpack, bcomb, h3);
  // 5. attention scores
  score_kernel<<<(NN * NH * 64 + 255) / 256, 256, 0, stream>>>(h3, att_src, att_dst,
                                                               s_src, s_dst);
  // 6. CSR build
  histogram<<<edgeBlocks, 256, 0, stream>>>(ei, counts);
  scan1<<<SCAN_BLOCKS, 256, 0, stream>>>(counts, expart, bsums);
  scan2<<<1, 256, 0, stream>>>(bsums);
  scan3<<<SCAN_BLOCKS, 256, 0, stream>>>(expart, bsums, rstart, cursor);
  // 7. scatter edges into CSR (pre-multiplied weights) + denom atomics
  scatter2<<<edgeBlocks, 256, 0, stream>>>(ei, eid, ddi, emb, s_src, s_dst, cursor,
                                           denom, slots);
  // 8. per-dst gather: 2 waves split edges, 2-edge unroll, no atomics
  gather4<<<NN, 128, 0, stream>>>(rstart, slots, h3, denom, bias_heads, out);
}

// Round 8
// 324.590 us; speedup vs baseline: 1.3108x; 1.2302x over previous
//
#include <hip/hip_runtime.h>
#include <math.h>

#define NN 50000
#define NE 600000
#define D 128
#define NH 3
#define SCAN_BLOCKS ((NN + 255) / 256)   // 196

typedef short bf16x8 __attribute__((ext_vector_type(8)));
typedef float f32x4 __attribute__((ext_vector_type(4)));

__device__ __forceinline__ unsigned short f2b(float f) {
  unsigned int u = __float_as_uint(f);
  u += 0x7FFF + ((u >> 16) & 1);          // round-to-nearest-even
  return (unsigned short)(u >> 16);
}
__device__ __forceinline__ float b2f(unsigned short h) {
  return __uint_as_float((unsigned int)h << 16);
}
__device__ __forceinline__ float blo(unsigned int u) {
  return __uint_as_float(u << 16);
}
__device__ __forceinline__ float bhi(unsigned int u) {
  return __uint_as_float(u & 0xffff0000u);
}

// ---------------------------------------------------------------------------
// GEMM (fp32, proven): used only for wcomb[h] = W_lin @ W_heads[h] (M=128).
// ---------------------------------------------------------------------------
__global__ __launch_bounds__(256) void gemm128(const float* __restrict__ X,
                                               const float* __restrict__ W,
                                               const float* __restrict__ bias,
                                               float* __restrict__ Y, int M,
                                               size_t wstride, size_t yoff,
                                               int pitch) {
  W += (size_t)blockIdx.y * wstride;
  Y += (size_t)blockIdx.y * yoff;
  __shared__ __align__(16) float xs[64][136];
  const int tid = threadIdx.x;
  const int row0 = blockIdx.x * 64;
  #pragma unroll
  for (int it = 0; it < 8; ++it) {
    int idx = tid + it * 256;
    int m = idx >> 5, k4 = idx & 31;
    float4 v = make_float4(0.f, 0.f, 0.f, 0.f);
    int row = row0 + m;
    if (row < M) v = ((const float4*)(X + (size_t)row * D))[k4];
    *((float4*)&xs[m][k4 * 4]) = v;
  }
  __syncthreads();
  const int tn = tid & 31;
  const int tm = tid >> 5;
  float acc[8][4];
  #pragma unroll
  for (int i = 0; i < 8; ++i)
    #pragma unroll
    for (int j = 0; j < 4; ++j) acc[i][j] = 0.f;

  for (int kb = 0; kb < 32; ++kb) {
    float4 b0 = ((const float4*)(W + (size_t)(kb * 4 + 0) * D))[tn];
    float4 b1 = ((const float4*)(W + (size_t)(kb * 4 + 1) * D))[tn];
    float4 b2 = ((const float4*)(W + (size_t)(kb * 4 + 2) * D))[tn];
    float4 b3 = ((const float4*)(W + (size_t)(kb * 4 + 3) * D))[tn];
    #pragma unroll
    for (int mi = 0; mi < 8; ++mi) {
      float4 a = *((const float4*)&xs[tm * 8 + mi][kb * 4]);
      acc[mi][0] += a.x * b0.x + a.y * b1.x + a.z * b2.x + a.w * b3.x;
      acc[mi][1] += a.x * b0.y + a.y * b1.y + a.z * b2.y + a.w * b3.y;
      acc[mi][2] += a.x * b0.z + a.y * b1.z + a.z * b2.z + a.w * b3.z;
      acc[mi][3] += a.x * b0.w + a.y * b1.w + a.z * b2.w + a.w * b3.w;
    }
  }
  float4 bv = make_float4(0.f, 0.f, 0.f, 0.f);
  if (bias) bv = ((const float4*)bias)[tn];
  #pragma unroll
  for (int mi = 0; mi < 8; ++mi) {
    int row = row0 + tm * 8 + mi;
    if (row < M) {
      float4 o;
      o.x = acc[mi][0] + bv.x;
      o.y = acc[mi][1] + bv.y;
      o.z = acc[mi][2] + bv.z;
      o.w = acc[mi][3] + bv.w;
      ((float4*)(Y + (size_t)row * pitch))[tn] = o;
    }
  }
}

// bcomb[h][n] = sum_k b_lin[k] * W_heads[h][k][n]
__global__ void prep_b(const float* __restrict__ b_lin,
                       const float* __restrict__ W_heads,
                       float* __restrict__ bcomb) {
  int t = blockIdx.x * 256 + threadIdx.x;
  if (t >= NH * D) return;
  int h = t / D, n = t - h * D;
  float acc = 0.f;
  for (int k = 0; k < D; ++k) acc += b_lin[k] * W_heads[h * D * D + k * D + n];
  bcomb[t] = acc;
}

// sbuf[h*2+0] = bcomb[h].att_src[h];  sbuf[h*2+1] = bcomb[h].att_dst[h]
__global__ void prep_sb(const float* __restrict__ bcomb,
                        const float* __restrict__ att_src,
                        const float* __restrict__ att_dst,
                        float* __restrict__ sbuf) {
  int t = threadIdx.x;
  if (t >= 2 * NH) return;
  int h = t >> 1;
  const float* a = (t & 1) ? (att_dst + h * D) : (att_src + h * D);
  float acc = 0.f;
  for (int k = 0; k < D; ++k) acc += bcomb[h * D + k] * a[k];
  sbuf[t] = acc;
}

// ---------------------------------------------------------------------------
// Pack B for MFMA. Per head 2304 units (9 column-tiles x 4 s x 4 q x 16 n0).
// nt<8: unit holds 8 bf16 { wcomb[k=s*32+q*8+j][n=nt*16+n0] }.
// nt==8: score columns — n0==0: Wcomb@att_src[k], n0==1: Wcomb@att_dst[k],
// n0>=2: zero. (scores become 2 extra GEMM output columns)
// ---------------------------------------------------------------------------
__global__ void pack_b2(const float* __restrict__ wcomb,
                        const float* __restrict__ att_src,
                        const float* __restrict__ att_dst,
                        uint4* __restrict__ Bpack) {
  int u = blockIdx.x * 256 + threadIdx.x;
  if (u >= NH * 2304) return;
  int h = u / 2304, r = u % 2304;
  int nt = r >> 8, s = (r >> 6) & 3, q = (r >> 4) & 3, n0 = r & 15;
  int kbase = s * 32 + q * 8;
  float vals[8];
  if (nt < 8) {
    const float* W = wcomb + h * D * D + kbase * D + nt * 16 + n0;
    #pragma unroll
    for (int j = 0; j < 8; ++j) vals[j] = W[j * D];
  } else if (n0 < 2) {
    const float* a = (n0 ? att_dst : att_src) + h * D;
    const float* W = wcomb + h * D * D + kbase * D;
    #pragma unroll
    for (int j = 0; j < 8; ++j) {
      float acc = 0.f;
      for (int m = 0; m < D; ++m) acc += W[j * D + m] * a[m];
      vals[j] = acc;
    }
  } else {
    #pragma unroll
    for (int j = 0; j < 8; ++j) vals[j] = 0.f;
  }
  unsigned int w[4];
  #pragma unroll
  for (int p = 0; p < 4; ++p)
    w[p] = (unsigned int)f2b(vals[2 * p]) | ((unsigned int)f2b(vals[2 * p + 1]) << 16);
  Bpack[u] = make_uint4(w[0], w[1], w[2], w[3]);
}

// ---------------------------------------------------------------------------
// h3[n][head][d] (bf16) = x @ wcomb[head] + bcomb[head] via MFMA 16x16x32,
// PLUS s_src/s_dst from the 9th column-tile (score columns 0/1).
// ---------------------------------------------------------------------------
__global__ __launch_bounds__(256) void mfma_h3s(const float* __restrict__ x,
                                                const uint4* __restrict__ Bpack,
                                                const float* __restrict__ bcomb,
                                                const float* __restrict__ sbuf,
                                                unsigned short* __restrict__ h3,
                                                float* __restrict__ s_src,
                                                float* __restrict__ s_dst) {
  const int head = blockIdx.y;
  const int row0 = blockIdx.x * 64;
  __shared__ __align__(16) unsigned short As[64][136];
  const int tid = threadIdx.x;
  #pragma unroll
  for (int it = 0; it < 8; ++it) {
    int idx = tid + it * 256;
    int m = idx >> 5, k4 = idx & 31;
    int row = row0 + m;
    float4 v = make_float4(0.f, 0.f, 0.f, 0.f);
    if (row < NN) v = ((const float4*)(x + (size_t)row * D))[k4];
    uint2 pk;
    pk.x = (unsigned int)f2b(v.x) | ((unsigned int)f2b(v.y) << 16);
    pk.y = (unsigned int)f2b(v.z) | ((unsigned int)f2b(v.w) << 16);
    *((uint2*)&As[m][k4 * 4]) = pk;
  }
  __syncthreads();
  const int wv = tid >> 6;
  const int lane = tid & 63;
  const int n0 = lane & 15, q = lane >> 4;
  const bf16x8* Bp = (const bf16x8*)(Bpack + head * 2304);

  f32x4 acc[9];
  #pragma unroll
  for (int nt = 0; nt < 9; ++nt) acc[nt] = (f32x4){0.f, 0.f, 0.f, 0.f};

  #pragma unroll
  for (int s = 0; s < 4; ++s) {
    bf16x8 a = *(const bf16x8*)&As[wv * 16 + n0][s * 32 + q * 8];
    #pragma unroll
    for (int nt = 0; nt < 9; ++nt) {
      bf16x8 b = Bp[(nt * 4 + s) * 64 + q * 16 + n0];
      acc[nt] = __builtin_amdgcn_mfma_f32_16x16x32_bf16(a, b, acc[nt], 0, 0, 0);
    }
  }
  const float* bc = bcomb + head * D;
  unsigned short* H = h3 + (size_t)head * D;
  #pragma unroll
  for (int nt = 0; nt < 8; ++nt) {
    int col = nt * 16 + n0;
    float bv = bc[col];
    #pragma unroll
    for (int r = 0; r < 4; ++r) {
      int row = row0 + wv * 16 + q * 4 + r;
      if (row < NN) H[(size_t)row * (NH * D) + col] = f2b(acc[nt][r] + bv);
    }
  }
  // score columns: n0==0 -> s_src, n0==1 -> s_dst  (C/D row = q*4+r)
  if (n0 < 2) {
    float sb = sbuf[head * 2 + n0];
    float* Sout = n0 ? s_dst : s_src;
    #pragma unroll
    for (int r = 0; r < 4; ++r) {
      int row = row0 + wv * 16 + q * 4 + r;
      if (row < NN) Sout[row * NH + head] = acc[8][r] + sb;
    }
  }
}

// --------------------------- CSR build (proven) ----------------------------
__global__ void histogram(const int* __restrict__ ei, int* __restrict__ counts) {
  int e = blockIdx.x * 256 + threadIdx.x;
  if (e < NE) atomicAdd(&counts[ei[NE + e]], 1);
}

__global__ __launch_bounds__(256) void scan1(const int* __restrict__ counts,
                                             int* __restrict__ expart,
                                             int* __restrict__ blocksums) {
  __shared__ int tmp[2][256];
  int i = blockIdx.x * 256 + threadIdx.x;
  int t = threadIdx.x;
  int v = (i < NN) ? counts[i] : 0;
  tmp[0][t] = v;
  __syncthreads();
  int cur = 0;
  #pragma unroll
  for (int off = 1; off < 256; off <<= 1) {
    int nv = tmp[cur][t] + (t >= off ? tmp[cur][t - off] : 0);
    tmp[1 - cur][t] = nv;
    cur = 1 - cur;
    __syncthreads();
  }
  if (i < NN) expart[i] = tmp[cur][t] - v;
  if (t == 255) blocksums[blockIdx.x] = tmp[cur][t];
}

__global__ __launch_bounds__(256) void scan2(int* __restrict__ blocksums) {
  __shared__ int tmp[2][256];
  int t = threadIdx.x;
  int v = (t < SCAN_BLOCKS) ? blocksums[t] : 0;
  tmp[0][t] = v;
  __syncthreads();
  int cur = 0;
  #pragma unroll
  for (int off = 1; off < 256; off <<= 1) {
    int nv = tmp[cur][t] + (t >= off ? tmp[cur][t - off] : 0);
    tmp[1 - cur][t] = nv;
    cur = 1 - cur;
    __syncthreads();
  }
  if (t < SCAN_BLOCKS) blocksums[t] = tmp[cur][t] - v;
}

__global__ void scan3(const int* __restrict__ expart, const int* __restrict__ blocksums,
                      int* __restrict__ row_start, int* __restrict__ cursor) {
  int i = blockIdx.x * 256 + threadIdx.x;
  if (i < NN) {
    int v = expart[i] + blocksums[blockIdx.x];
    row_start[i] = v;
    cursor[i] = v;
  }
  if (i == 0) row_start[NN] = NE;
}

// ---------------------------------------------------------------------------
// Scatter (r5 proven): slots[slot] = {bitcast(src), p0, p1, p2}; ews stream.
// One int cursor atomic per edge only — NO float atomics.
// ---------------------------------------------------------------------------
__global__ __launch_bounds__(256) void scatter(const int* __restrict__ ei,
                                               const int* __restrict__ eid,
                                               const float* __restrict__ ddi,
                                               const float* __restrict__ emb,
                                               const float* __restrict__ s_src,
                                               const float* __restrict__ s_dst,
                                               int* __restrict__ cursor,
                                               float4* __restrict__ slots,
                                               float* __restrict__ ews) {
  int e = blockIdx.x * 256 + threadIdx.x;
  if (e >= NE) return;
  int src = ei[e], dst = ei[NE + e];
  int slot = atomicAdd(&cursor[dst], 1);
  float p[NH];
  #pragma unroll
  for (int hd = 0; hd < NH; ++hd) {
    float v = s_src[src * NH + hd] + s_dst[dst * NH + hd];
    v = v > 0.f ? v : 0.2f * v;
    p[hd] = __expf(v);   // no max-subtraction: |v| <= ~10, exp safe in fp32
  }
  slots[slot] = make_float4(__int_as_float(src), p[0], p[1], p[2]);
  ews[slot] = emb[eid[e]] - ddi[e];
}

// ---------------------------------------------------------------------------
// Gather v5: one dst per 128-thr block; 2 waves split the CSR row in half
// (no redundant per-edge work), 2-edge unroll. Denominators accumulated
// inline (3 FADD/edge), combined with the 6 partial sums via LDS.
// No atomics; out written exactly once.
// ---------------------------------------------------------------------------
__global__ __launch_bounds__(128) void gather5(const int* __restrict__ row_start,
                                               const float4* __restrict__ slots,
                                               const float* __restrict__ ews,
                                               const unsigned short* __restrict__ h3,
                                               const float* __restrict__ bias_heads,
                                               float* __restrict__ out) {
  __shared__ float sm[6][64];
  __shared__ float smden[3];
  const int dst = blockIdx.x;
  const int wv = threadIdx.x >> 6;
  const int lane = threadIdx.x & 63;
  const int c = lane * 2;
  const int beg = row_start[dst], end = row_start[dst + 1];
  const int mid = (beg + end) >> 1;
  int s = wv ? mid : beg;
  const int s1 = wv ? end : mid;
  float a00 = 0.f, a01 = 0.f, a10 = 0.f, a11 = 0.f, a20 = 0.f, a21 = 0.f;
  float d0 = 0.f, d1 = 0.f, d2 = 0.f;
  for (; s + 1 < s1; s += 2) {
    float4 A = slots[s], B = slots[s + 1];
    float ewa = ews[s], ewb = ews[s + 1];
    const unsigned short* ha = h3 + (size_t)__float_as_int(A.x) * (NH * D);
    const unsigned short* hb = h3 + (size_t)__float_as_int(B.x) * (NH * D);
    unsigned int ua0 = *(const unsigned int*)&ha[c];
    unsigned int ua1 = *(const unsigned int*)&ha[D + c];
    unsigned int ua2 = *(const unsigned int*)&ha[2 * D + c];
    unsigned int ub0 = *(const unsigned int*)&hb[c];
    unsigned int ub1 = *(const unsigned int*)&hb[D + c];
    unsigned int ub2 = *(const unsigned int*)&hb[2 * D + c];
    float wa0 = A.y * ewa, wa1 = A.z * ewa, wa2 = A.w * ewa;
    float wb0 = B.y * ewb, wb1 = B.z * ewb, wb2 = B.w * ewb;
    a00 += wa0 * blo(ua0) + wb0 * blo(ub0);
    a01 += wa0 * bhi(ua0) + wb0 * bhi(ub0);
    a10 += wa1 * blo(ua1) + wb1 * blo(ub1);
    a11 += wa1 * bhi(ua1) + wb1 * bhi(ub1);
    a20 += wa2 * blo(ua2) + wb2 * blo(ub2);
    a21 += wa2 * bhi(ua2) + wb2 * bhi(ub2);
    d0 += A.y + B.y;
    d1 += A.z + B.z;
    d2 += A.w + B.w;
  }
  if (s < s1) {
    float4 A = slots[s];
    float ewa = ews[s];
    const unsigned short* ha = h3 + (size_t)__float_as_int(A.x) * (NH * D);
    unsigned int ua0 = *(const unsigned int*)&ha[c];
    unsigned int ua1 = *(const unsigned int*)&ha[D + c];
    unsigned int ua2 = *(const unsigned int*)&ha[2 * D + c];
    float wa0 = A.y * ewa, wa1 = A.z * ewa, wa2 = A.w * ewa;
    a00 += wa0 * blo(ua0);
    a01 += wa0 * bhi(ua0);
    a10 += wa1 * blo(ua1);
    a11 += wa1 * bhi(ua1);
    a20 += wa2 * blo(ua2);
    a21 += wa2 * bhi(ua2);
    d0 += A.y;
    d1 += A.z;
    d2 += A.w;
  }
  if (wv == 1) {
    sm[0][lane] = a00; sm[1][lane] = a01;
    sm[2][lane] = a10; sm[3][lane] = a11;
    sm[4][lane] = a20; sm[5][lane] = a21;
    if (lane == 0) { smden[0] = d0; smden[1] = d1; smden[2] = d2; }
  }
  __syncthreads();
  if (wv == 0) {
    a00 += sm[0][lane]; a01 += sm[1][lane];
    a10 += sm[2][lane]; a11 += sm[3][lane];
    a20 += sm[4][lane]; a21 += sm[5][lane];
    float r0 = 1.f / fmaxf(d0 + smden[0], 1e-16f);
    float r1 = 1.f / fmaxf(d1 + smden[1], 1e-16f);
    float r2 = 1.f / fmaxf(d2 + smden[2], 1e-16f);
    float o0 = a00 * r0 + a10 * r1 + a20 * r2 +
               bias_heads[c] + bias_heads[D + c] + bias_heads[2 * D + c];
    float o1 = a01 * r0 + a11 * r1 + a21 * r2 +
               bias_heads[c + 1] + bias_heads[D + c + 1] + bias_heads[2 * D + c + 1];
    *((float2*)&out[(size_t)dst * D + c]) = make_float2(o0 * (1.f / 3.f),
                                                        o1 * (1.f / 3.f));
  }
}

// ---------------------------------------------------------------------------
extern "C" void kernel_launch(void* const* d_in, const int* in_sizes, int n_in,
                              void* d_out, int out_size, void* d_ws, size_t ws_size,
                              hipStream_t stream) {
  const float* x          = (const float*)d_in[0];
  const int*   ei         = (const int*)d_in[1];
  const int*   eid        = (const int*)d_in[2];
  const float* ddi        = (const float*)d_in[3];
  const float* W_lin      = (const float*)d_in[4];
  const float* b_lin      = (const float*)d_in[5];
  const float* emb        = (const float*)d_in[6];
  const float* W_heads    = (const float*)d_in[7];
  const float* att_src    = (const float*)d_in[8];
  const float* att_dst    = (const float*)d_in[9];
  const float* bias_heads = (const float*)d_in[10];
  float* out = (float*)d_out;

  // workspace layout (16B-aligned chunks first)
  float4* slots  = (float4*)d_ws;                              // NE
  uint4*  Bpack  = (uint4*)(slots + NE);                       // NH*2304
  unsigned short* h3 = (unsigned short*)(Bpack + NH * 2304);   // NN*NH*D bf16
  float*  wcomb  = (float*)(h3 + (size_t)NN * NH * D);         // NH*D*D
  float*  ews    = wcomb + NH * D * D;                         // NE
  float*  bcomb  = ews + NE;                                   // NH*D
  float*  sbuf   = bcomb + NH * D;                             // 8
  float*  s_src  = sbuf + 8;                                   // NN*NH
  float*  s_dst  = s_src + NN * NH;                            // NN*NH
  int*    counts = (int*)(s_dst + NN * NH);                    // NN (zeroed)
  int*    expart = counts + NN;                                // NN
  int*    bsums  = expart + NN;                                // 256
  int*    rstart = bsums + 256;                                // NN+1
  int*    cursor = rstart + NN + 1;                            // NN

  const int edgeBlocks = (NE + 255) / 256;

  // 0. zero edge-count histogram
  hipMemsetAsync(counts, 0, (size_t)NN * sizeof(int), stream);
  // 1. wcomb[h] = W_lin @ W_heads[h]
  gemm128<<<dim3(2, NH), 256, 0, stream>>>(W_lin, W_heads, nullptr, wcomb, D,
                                           (size_t)D * D, (size_t)D * D, D);
  // 2. bcomb[h] = b_lin @ W_heads[h]
  prep_b<<<(NH * D + 255) / 256, 256, 0, stream>>>(b_lin, W_heads, bcomb);
  // 3. score bias terms
  prep_sb<<<1, 64, 0, stream>>>(bcomb, att_src, att_dst, sbuf);
  // 4. Bpack = bf16 fragment-ordered wcomb + score columns
  pack_b2<<<(NH * 2304 + 255) / 256, 256, 0, stream>>>(wcomb, att_src, att_dst, Bpack);
  // 5. h3 + s_src/s_dst in one MFMA pass
  mfma_h3s<<<dim3((NN + 63) / 64, NH), 256, 0, stream>>>(x, Bpack, bcomb, sbuf,
                                                         h3, s_src, s_dst);
  // 6. CSR build
  histogram<<<edgeBlocks, 256, 0, stream>>>(ei, counts);
  scan1<<<SCAN_BLOCKS, 256, 0, stream>>>(counts, expart, bsums);
  scan2<<<1, 256, 0, stream>>>(bsums);
  scan3<<<SCAN_BLOCKS, 256, 0, stream>>>(expart, bsums, rstart, cursor);
  // 7. scatter edges into CSR (int cursor atomic only)
  scatter<<<edgeBlocks, 256, 0, stream>>>(ei, eid, ddi, emb, s_src, s_dst, cursor,
                                          slots, ews);
  // 8. per-dst gather: 2-wave edge split, inline denominators, no atomics
  gather5<<<NN, 128, 0, stream>>>(rstart, slots, ews, h3, bias_heads, out);
}

// Round 9
// 320.201 us; speedup vs baseline: 1.3288x; 1.0137x over previous
//
#include <hip/hip_runtime.h>
#include <math.h>

#define NN 50000
#define NE 600000
#define D 128
#define NH 3
#define SCAN_BLOCKS ((NN + 255) / 256)   // 196

typedef short bf16x8 __attribute__((ext_vector_type(8)));
typedef float f32x4 __attribute__((ext_vector_type(4)));

__device__ __forceinline__ unsigned short f2b(float f) {
  unsigned int u = __float_as_uint(f);
  u += 0x7FFF + ((u >> 16) & 1);          // round-to-nearest-even
  return (unsigned short)(u >> 16);
}
__device__ __forceinline__ float b2f(unsigned short h) {
  return __uint_as_float((unsigned int)h << 16);
}
__device__ __forceinline__ float blo(unsigned int u) {
  return __uint_as_float(u << 16);
}
__device__ __forceinline__ float bhi(unsigned int u) {
  return __uint_as_float(u & 0xffff0000u);
}

// ---------------------------------------------------------------------------
// GEMM (fp32, proven): used only for wcomb[h] = W_lin @ W_heads[h] (M=128).
// ---------------------------------------------------------------------------
__global__ __launch_bounds__(256) void gemm128(const float* __restrict__ X,
                                               const float* __restrict__ W,
                                               const float* __restrict__ bias,
                                               float* __restrict__ Y, int M,
                                               size_t wstride, size_t yoff,
                                               int pitch) {
  W += (size_t)blockIdx.y * wstride;
  Y += (size_t)blockIdx.y * yoff;
  __shared__ __align__(16) float xs[64][136];
  const int tid = threadIdx.x;
  const int row0 = blockIdx.x * 64;
  #pragma unroll
  for (int it = 0; it < 8; ++it) {
    int idx = tid + it * 256;
    int m = idx >> 5, k4 = idx & 31;
    float4 v = make_float4(0.f, 0.f, 0.f, 0.f);
    int row = row0 + m;
    if (row < M) v = ((const float4*)(X + (size_t)row * D))[k4];
    *((float4*)&xs[m][k4 * 4]) = v;
  }
  __syncthreads();
  const int tn = tid & 31;
  const int tm = tid >> 5;
  float acc[8][4];
  #pragma unroll
  for (int i = 0; i < 8; ++i)
    #pragma unroll
    for (int j = 0; j < 4; ++j) acc[i][j] = 0.f;

  for (int kb = 0; kb < 32; ++kb) {
    float4 b0 = ((const float4*)(W + (size_t)(kb * 4 + 0) * D))[tn];
    float4 b1 = ((const float4*)(W + (size_t)(kb * 4 + 1) * D))[tn];
    float4 b2 = ((const float4*)(W + (size_t)(kb * 4 + 2) * D))[tn];
    float4 b3 = ((const float4*)(W + (size_t)(kb * 4 + 3) * D))[tn];
    #pragma unroll
    for (int mi = 0; mi < 8; ++mi) {
      float4 a = *((const float4*)&xs[tm * 8 + mi][kb * 4]);
      acc[mi][0] += a.x * b0.x + a.y * b1.x + a.z * b2.x + a.w * b3.x;
      acc[mi][1] += a.x * b0.y + a.y * b1.y + a.z * b2.y + a.w * b3.y;
      acc[mi][2] += a.x * b0.z + a.y * b1.z + a.z * b2.z + a.w * b3.z;
      acc[mi][3] += a.x * b0.w + a.y * b1.w + a.z * b2.w + a.w * b3.w;
    }
  }
  float4 bv = make_float4(0.f, 0.f, 0.f, 0.f);
  if (bias) bv = ((const float4*)bias)[tn];
  #pragma unroll
  for (int mi = 0; mi < 8; ++mi) {
    int row = row0 + tm * 8 + mi;
    if (row < M) {
      float4 o;
      o.x = acc[mi][0] + bv.x;
      o.y = acc[mi][1] + bv.y;
      o.z = acc[mi][2] + bv.z;
      o.w = acc[mi][3] + bv.w;
      ((float4*)(Y + (size_t)row * pitch))[tn] = o;
    }
  }
}

// bcomb[h][n] = sum_k b_lin[k] * W_heads[h][k][n]
__global__ void prep_b(const float* __restrict__ b_lin,
                       const float* __restrict__ W_heads,
                       float* __restrict__ bcomb) {
  int t = blockIdx.x * 256 + threadIdx.x;
  if (t >= NH * D) return;
  int h = t / D, n = t - h * D;
  float acc = 0.f;
  for (int k = 0; k < D; ++k) acc += b_lin[k] * W_heads[h * D * D + k * D + n];
  bcomb[t] = acc;
}

// sbuf[h*2+0] = bcomb[h].att_src[h];  sbuf[h*2+1] = bcomb[h].att_dst[h]
__global__ void prep_sb(const float* __restrict__ bcomb,
                        const float* __restrict__ att_src,
                        const float* __restrict__ att_dst,
                        float* __restrict__ sbuf) {
  int t = threadIdx.x;
  if (t >= 2 * NH) return;
  int h = t >> 1;
  const float* a = (t & 1) ? (att_dst + h * D) : (att_src + h * D);
  float acc = 0.f;
  for (int k = 0; k < D; ++k) acc += bcomb[h * D + k] * a[k];
  sbuf[t] = acc;
}

// ---------------------------------------------------------------------------
// Pack B for MFMA. Per head 2304 units (9 column-tiles x 4 s x 4 q x 16 n0).
// nt<8: unit holds 8 bf16 { wcomb[k=s*32+q*8+j][n=nt*16+n0] }.
// nt==8: score columns — n0==0: Wcomb@att_src[k], n0==1: Wcomb@att_dst[k],
// n0>=2: zero. (scores become 2 extra GEMM output columns)
// ---------------------------------------------------------------------------
__global__ void pack_b2(const float* __restrict__ wcomb,
                        const float* __restrict__ att_src,
                        const float* __restrict__ att_dst,
                        uint4* __restrict__ Bpack) {
  int u = blockIdx.x * 256 + threadIdx.x;
  if (u >= NH * 2304) return;
  int h = u / 2304, r = u % 2304;
  int nt = r >> 8, s = (r >> 6) & 3, q = (r >> 4) & 3, n0 = r & 15;
  int kbase = s * 32 + q * 8;
  float vals[8];
  if (nt < 8) {
    const float* W = wcomb + h * D * D + kbase * D + nt * 16 + n0;
    #pragma unroll
    for (int j = 0; j < 8; ++j) vals[j] = W[j * D];
  } else if (n0 < 2) {
    const float* a = (n0 ? att_dst : att_src) + h * D;
    const float* W = wcomb + h * D * D + kbase * D;
    #pragma unroll
    for (int j = 0; j < 8; ++j) {
      float acc = 0.f;
      for (int m = 0; m < D; ++m) acc += W[j * D + m] * a[m];
      vals[j] = acc;
    }
  } else {
    #pragma unroll
    for (int j = 0; j < 8; ++j) vals[j] = 0.f;
  }
  unsigned int w[4];
  #pragma unroll
  for (int p = 0; p < 4; ++p)
    w[p] = (unsigned int)f2b(vals[2 * p]) | ((unsigned int)f2b(vals[2 * p + 1]) << 16);
  Bpack[u] = make_uint4(w[0], w[1], w[2], w[3]);
}

// ---------------------------------------------------------------------------
// h3[n][head][d] (bf16) = x @ wcomb[head] + bcomb[head] via MFMA 16x16x32,
// PLUS s_src/s_dst from the 9th column-tile (score columns 0/1).
// ---------------------------------------------------------------------------
__global__ __launch_bounds__(256) void mfma_h3s(const float* __restrict__ x,
                                                const uint4* __restrict__ Bpack,
                                                const float* __restrict__ bcomb,
                                                const float* __restrict__ sbuf,
                                                unsigned short* __restrict__ h3,
                                                float* __restrict__ s_src,
                                                float* __restrict__ s_dst) {
  const int head = blockIdx.y;
  const int row0 = blockIdx.x * 64;
  __shared__ __align__(16) unsigned short As[64][136];
  const int tid = threadIdx.x;
  #pragma unroll
  for (int it = 0; it < 8; ++it) {
    int idx = tid + it * 256;
    int m = idx >> 5, k4 = idx & 31;
    int row = row0 + m;
    float4 v = make_float4(0.f, 0.f, 0.f, 0.f);
    if (row < NN) v = ((const float4*)(x + (size_t)row * D))[k4];
    uint2 pk;
    pk.x = (unsigned int)f2b(v.x) | ((unsigned int)f2b(v.y) << 16);
    pk.y = (unsigned int)f2b(v.z) | ((unsigned int)f2b(v.w) << 16);
    *((uint2*)&As[m][k4 * 4]) = pk;
  }
  __syncthreads();
  const int wv = tid >> 6;
  const int lane = tid & 63;
  const int n0 = lane & 15, q = lane >> 4;
  const bf16x8* Bp = (const bf16x8*)(Bpack + head * 2304);

  f32x4 acc[9];
  #pragma unroll
  for (int nt = 0; nt < 9; ++nt) acc[nt] = (f32x4){0.f, 0.f, 0.f, 0.f};

  #pragma unroll
  for (int s = 0; s < 4; ++s) {
    bf16x8 a = *(const bf16x8*)&As[wv * 16 + n0][s * 32 + q * 8];
    #pragma unroll
    for (int nt = 0; nt < 9; ++nt) {
      bf16x8 b = Bp[(nt * 4 + s) * 64 + q * 16 + n0];
      acc[nt] = __builtin_amdgcn_mfma_f32_16x16x32_bf16(a, b, acc[nt], 0, 0, 0);
    }
  }
  const float* bc = bcomb + head * D;
  unsigned short* H = h3 + (size_t)head * D;
  #pragma unroll
  for (int nt = 0; nt < 8; ++nt) {
    int col = nt * 16 + n0;
    float bv = bc[col];
    #pragma unroll
    for (int r = 0; r < 4; ++r) {
      int row = row0 + wv * 16 + q * 4 + r;
      if (row < NN) H[(size_t)row * (NH * D) + col] = f2b(acc[nt][r] + bv);
    }
  }
  // score columns: n0==0 -> s_src, n0==1 -> s_dst  (C/D row = q*4+r)
  if (n0 < 2) {
    float sb = sbuf[head * 2 + n0];
    float* Sout = n0 ? s_dst : s_src;
    #pragma unroll
    for (int r = 0; r < 4; ++r) {
      int row = row0 + wv * 16 + q * 4 + r;
      if (row < NN) Sout[row * NH + head] = acc[8][r] + sb;
    }
  }
}

// --------------------------- CSR build (proven) ----------------------------
__global__ void histogram(const int* __restrict__ ei, int* __restrict__ counts) {
  int e = blockIdx.x * 256 + threadIdx.x;
  if (e < NE) atomicAdd(&counts[ei[NE + e]], 1);
}

__global__ __launch_bounds__(256) void scan1(const int* __restrict__ counts,
                                             int* __restrict__ expart,
                                             int* __restrict__ blocksums) {
  __shared__ int tmp[2][256];
  int i = blockIdx.x * 256 + threadIdx.x;
  int t = threadIdx.x;
  int v = (i < NN) ? counts[i] : 0;
  tmp[0][t] = v;
  __syncthreads();
  int cur = 0;
  #pragma unroll
  for (int off = 1; off < 256; off <<= 1) {
    int nv = tmp[cur][t] + (t >= off ? tmp[cur][t - off] : 0);
    tmp[1 - cur][t] = nv;
    cur = 1 - cur;
    __syncthreads();
  }
  if (i < NN) expart[i] = tmp[cur][t] - v;
  if (t == 255) blocksums[blockIdx.x] = tmp[cur][t];
}

__global__ __launch_bounds__(256) void scan2(int* __restrict__ blocksums) {
  __shared__ int tmp[2][256];
  int t = threadIdx.x;
  int v = (t < SCAN_BLOCKS) ? blocksums[t] : 0;
  tmp[0][t] = v;
  __syncthreads();
  int cur = 0;
  #pragma unroll
  for (int off = 1; off < 256; off <<= 1) {
    int nv = tmp[cur][t] + (t >= off ? tmp[cur][t - off] : 0);
    tmp[1 - cur][t] = nv;
    cur = 1 - cur;
    __syncthreads();
  }
  if (t < SCAN_BLOCKS) blocksums[t] = tmp[cur][t] - v;
}

__global__ void scan3(const int* __restrict__ expart, const int* __restrict__ blocksums,
                      int* __restrict__ row_start, int* __restrict__ cursor) {
  int i = blockIdx.x * 256 + threadIdx.x;
  if (i < NN) {
    int v = expart[i] + blocksums[blockIdx.x];
    row_start[i] = v;
    cursor[i] = v;
  }
  if (i == 0) row_start[NN] = NE;
}

// ---------------------------------------------------------------------------
// Scatter (proven): slots[slot] = {bitcast(src), p0, p1, p2}; ews stream.
// One int cursor atomic per edge only — NO float atomics.
// ---------------------------------------------------------------------------
__global__ __launch_bounds__(256) void scatter(const int* __restrict__ ei,
                                               const int* __restrict__ eid,
                                               const float* __restrict__ ddi,
                                               const float* __restrict__ emb,
                                               const float* __restrict__ s_src,
                                               const float* __restrict__ s_dst,
                                               int* __restrict__ cursor,
                                               float4* __restrict__ slots,
                                               float* __restrict__ ews) {
  int e = blockIdx.x * 256 + threadIdx.x;
  if (e >= NE) return;
  int src = ei[e], dst = ei[NE + e];
  int slot = atomicAdd(&cursor[dst], 1);
  float p[NH];
  #pragma unroll
  for (int hd = 0; hd < NH; ++hd) {
    float v = s_src[src * NH + hd] + s_dst[dst * NH + hd];
    v = v > 0.f ? v : 0.2f * v;
    p[hd] = __expf(v);   // no max-subtraction: |v| <= ~10, exp safe in fp32
  }
  slots[slot] = make_float4(__int_as_float(src), p[0], p[1], p[2]);
  ews[slot] = emb[eid[e]] - ddi[e];
}

// ---------------------------------------------------------------------------
// Gather v6: ONE WAVE per dst (block=64, no LDS/barrier). Lanes 0-31 process
// even CSR slots, lanes 32-63 odd slots (2 edges in flight per wave instr).
// Each lane covers 4 channels x 3 heads via uint2 loads (+imm offsets), so
// 3 load-instrs serve 2 edges. Halves combined via shfl_xor(32); lanes 0-31
// write one coalesced float4. Denominators accumulated inline. No atomics.
// ---------------------------------------------------------------------------
__global__ __launch_bounds__(64) void gather6(const int* __restrict__ row_start,
                                              const float4* __restrict__ slots,
                                              const float* __restrict__ ews,
                                              const unsigned short* __restrict__ h3,
                                              const float* __restrict__ bias_heads,
                                              float* __restrict__ out) {
  const int dst = blockIdx.x;
  const int lane = threadIdx.x;          // 0..63
  const int half = lane >> 5;
  const int c = (lane & 31) * 4;         // channel base (4 channels per lane)
  const int beg = row_start[dst], end = row_start[dst + 1];
  float a0[4] = {0.f, 0.f, 0.f, 0.f};
  float a1[4] = {0.f, 0.f, 0.f, 0.f};
  float a2[4] = {0.f, 0.f, 0.f, 0.f};
  float d0 = 0.f, d1 = 0.f, d2 = 0.f;
  for (int s = beg + half; s < end; s += 2) {
    float4 A = slots[s];
    float ew = ews[s];
    const unsigned short* hp = h3 + (size_t)__float_as_int(A.x) * (NH * D);
    uint2 u0 = *(const uint2*)&hp[c];
    uint2 u1 = *(const uint2*)&hp[D + c];
    uint2 u2 = *(const uint2*)&hp[2 * D + c];
    float w0 = A.y * ew, w1 = A.z * ew, w2 = A.w * ew;
    a0[0] += w0 * blo(u0.x); a0[1] += w0 * bhi(u0.x);
    a0[2] += w0 * blo(u0.y); a0[3] += w0 * bhi(u0.y);
    a1[0] += w1 * blo(u1.x); a1[1] += w1 * bhi(u1.x);
    a1[2] += w1 * blo(u1.y); a1[3] += w1 * bhi(u1.y);
    a2[0] += w2 * blo(u2.x); a2[1] += w2 * bhi(u2.x);
    a2[2] += w2 * blo(u2.y); a2[3] += w2 * bhi(u2.y);
    d0 += A.y; d1 += A.z; d2 += A.w;
  }
  // combine the two half-wave edge streams
  #pragma unroll
  for (int j = 0; j < 4; ++j) {
    a0[j] += __shfl_xor(a0[j], 32, 64);
    a1[j] += __shfl_xor(a1[j], 32, 64);
    a2[j] += __shfl_xor(a2[j], 32, 64);
  }
  d0 += __shfl_xor(d0, 32, 64);
  d1 += __shfl_xor(d1, 32, 64);
  d2 += __shfl_xor(d2, 32, 64);
  if (half == 0) {
    float r0 = 1.f / fmaxf(d0, 1e-16f);
    float r1 = 1.f / fmaxf(d1, 1e-16f);
    float r2 = 1.f / fmaxf(d2, 1e-16f);
    float4 b0 = ((const float4*)bias_heads)[lane & 31];
    float4 b1 = ((const float4*)bias_heads)[32 + (lane & 31)];
    float4 b2 = ((const float4*)bias_heads)[64 + (lane & 31)];
    float4 o;
    o.x = (a0[0] * r0 + a1[0] * r1 + a2[0] * r2 + b0.x + b1.x + b2.x) * (1.f / 3.f);
    o.y = (a0[1] * r0 + a1[1] * r1 + a2[1] * r2 + b0.y + b1.y + b2.y) * (1.f / 3.f);
    o.z = (a0[2] * r0 + a1[2] * r1 + a2[2] * r2 + b0.z + b1.z + b2.z) * (1.f / 3.f);
    o.w = (a0[3] * r0 + a1[3] * r1 + a2[3] * r2 + b0.w + b1.w + b2.w) * (1.f / 3.f);
    *((float4*)&out[(size_t)dst * D + c]) = o;
  }
}

// ---------------------------------------------------------------------------
extern "C" void kernel_launch(void* const* d_in, const int* in_sizes, int n_in,
                              void* d_out, int out_size, void* d_ws, size_t ws_size,
                              hipStream_t stream) {
  const float* x          = (const float*)d_in[0];
  const int*   ei         = (const int*)d_in[1];
  const int*   eid        = (const int*)d_in[2];
  const float* ddi        = (const float*)d_in[3];
  const float* W_lin      = (const float*)d_in[4];
  const float* b_lin      = (const float*)d_in[5];
  const float* emb        = (const float*)d_in[6];
  const float* W_heads    = (const float*)d_in[7];
  const float* att_src    = (const float*)d_in[8];
  const float* att_dst    = (const float*)d_in[9];
  const float* bias_heads = (const float*)d_in[10];
  float* out = (float*)d_out;

  // workspace layout (16B-aligned chunks first)
  float4* slots  = (float4*)d_ws;                              // NE
  uint4*  Bpack  = (uint4*)(slots + NE);                       // NH*2304
  unsigned short* h3 = (unsigned short*)(Bpack + NH * 2304);   // NN*NH*D bf16
  float*  wcomb  = (float*)(h3 + (size_t)NN * NH * D);         // NH*D*D
  float*  ews    = wcomb + NH * D * D;                         // NE
  float*  bcomb  = ews + NE;                                   // NH*D
  float*  sbuf   = bcomb + NH * D;                             // 8
  float*  s_src  = sbuf + 8;                                   // NN*NH
  float*  s_dst  = s_src + NN * NH;                            // NN*NH
  int*    counts = (int*)(s_dst + NN * NH);                    // NN (zeroed)
  int*    expart = counts + NN;                                // NN
  int*    bsums  = expart + NN;                                // 256
  int*    rstart = bsums + 256;                                // NN+1
  int*    cursor = rstart + NN + 1;                            // NN

  const int edgeBlocks = (NE + 255) / 256;

  // 0. zero edge-count histogram
  hipMemsetAsync(counts, 0, (size_t)NN * sizeof(int), stream);
  // 1. wcomb[h] = W_lin @ W_heads[h]
  gemm128<<<dim3(2, NH), 256, 0, stream>>>(W_lin, W_heads, nullptr, wcomb, D,
                                           (size_t)D * D, (size_t)D * D, D);
  // 2. bcomb[h] = b_lin @ W_heads[h]
  prep_b<<<(NH * D + 255) / 256, 256, 0, stream>>>(b_lin, W_heads, bcomb);
  // 3. score bias terms
  prep_sb<<<1, 64, 0, stream>>>(bcomb, att_src, att_dst, sbuf);
  // 4. Bpack = bf16 fragment-ordered wcomb + score columns
  pack_b2<<<(NH * 2304 + 255) / 256, 256, 0, stream>>>(wcomb, att_src, att_dst, Bpack);
  // 5. h3 + s_src/s_dst in one MFMA pass
  mfma_h3s<<<dim3((NN + 63) / 64, NH), 256, 0, stream>>>(x, Bpack, bcomb, sbuf,
                                                         h3, s_src, s_dst);
  // 6. CSR build
  histogram<<<edgeBlocks, 256, 0, stream>>>(ei, counts);
  scan1<<<SCAN_BLOCKS, 256, 0, stream>>>(counts, expart, bsums);
  scan2<<<1, 256, 0, stream>>>(bsums);
  scan3<<<SCAN_BLOCKS, 256, 0, stream>>>(expart, bsums, rstart, cursor);
  // 7. scatter edges into CSR (int cursor atomic only)
  scatter<<<edgeBlocks, 256, 0, stream>>>(ei, eid, ddi, emb, s_src, s_dst, cursor,
                                          slots, ews);
  // 8. per-dst gather: 1 wave/dst, dual-edge half-wave streams, no atomics
  gather6<<<NN, 64, 0, stream>>>(rstart, slots, ews, h3, bias_heads, out);
}

// Round 10
// 297.210 us; speedup vs baseline: 1.4316x; 1.0774x over previous
//
#include <hip/hip_runtime.h>
#include <math.h>

#define NN 50000
#define NE 600000
#define D 128
#define NH 3
#define SCAN_BLOCKS ((NN + 255) / 256)   // 196

typedef short bf16x8 __attribute__((ext_vector_type(8)));
typedef float f32x4 __attribute__((ext_vector_type(4)));

__device__ __forceinline__ unsigned short f2b(float f) {
  unsigned int u = __float_as_uint(f);
  u += 0x7FFF + ((u >> 16) & 1);          // round-to-nearest-even
  return (unsigned short)(u >> 16);
}
__device__ __forceinline__ float b2f(unsigned short h) {
  return __uint_as_float((unsigned int)h << 16);
}
__device__ __forceinline__ float blo(unsigned int u) {
  return __uint_as_float(u << 16);
}
__device__ __forceinline__ float bhi(unsigned int u) {
  return __uint_as_float(u & 0xffff0000u);
}

// ---------------------------------------------------------------------------
// GEMM (fp32, proven): wcomb[h] = W_lin @ W_heads[h] (M=128, 6 blocks).
// ---------------------------------------------------------------------------
__global__ __launch_bounds__(256) void gemm128(const float* __restrict__ X,
                                               const float* __restrict__ W,
                                               const float* __restrict__ bias,
                                               float* __restrict__ Y, int M,
                                               size_t wstride, size_t yoff,
                                               int pitch) {
  W += (size_t)blockIdx.y * wstride;
  Y += (size_t)blockIdx.y * yoff;
  __shared__ __align__(16) float xs[64][136];
  const int tid = threadIdx.x;
  const int row0 = blockIdx.x * 64;
  #pragma unroll
  for (int it = 0; it < 8; ++it) {
    int idx = tid + it * 256;
    int m = idx >> 5, k4 = idx & 31;
    float4 v = make_float4(0.f, 0.f, 0.f, 0.f);
    int row = row0 + m;
    if (row < M) v = ((const float4*)(X + (size_t)row * D))[k4];
    *((float4*)&xs[m][k4 * 4]) = v;
  }
  __syncthreads();
  const int tn = tid & 31;
  const int tm = tid >> 5;
  float acc[8][4];
  #pragma unroll
  for (int i = 0; i < 8; ++i)
    #pragma unroll
    for (int j = 0; j < 4; ++j) acc[i][j] = 0.f;

  for (int kb = 0; kb < 32; ++kb) {
    float4 b0 = ((const float4*)(W + (size_t)(kb * 4 + 0) * D))[tn];
    float4 b1 = ((const float4*)(W + (size_t)(kb * 4 + 1) * D))[tn];
    float4 b2 = ((const float4*)(W + (size_t)(kb * 4 + 2) * D))[tn];
    float4 b3 = ((const float4*)(W + (size_t)(kb * 4 + 3) * D))[tn];
    #pragma unroll
    for (int mi = 0; mi < 8; ++mi) {
      float4 a = *((const float4*)&xs[tm * 8 + mi][kb * 4]);
      acc[mi][0] += a.x * b0.x + a.y * b1.x + a.z * b2.x + a.w * b3.x;
      acc[mi][1] += a.x * b0.y + a.y * b1.y + a.z * b2.y + a.w * b3.y;
      acc[mi][2] += a.x * b0.z + a.y * b1.z + a.z * b2.z + a.w * b3.z;
      acc[mi][3] += a.x * b0.w + a.y * b1.w + a.z * b2.w + a.w * b3.w;
    }
  }
  float4 bv = make_float4(0.f, 0.f, 0.f, 0.f);
  if (bias) bv = ((const float4*)bias)[tn];
  #pragma unroll
  for (int mi = 0; mi < 8; ++mi) {
    int row = row0 + tm * 8 + mi;
    if (row < M) {
      float4 o;
      o.x = acc[mi][0] + bv.x;
      o.y = acc[mi][1] + bv.y;
      o.z = acc[mi][2] + bv.z;
      o.w = acc[mi][3] + bv.w;
      ((float4*)(Y + (size_t)row * pitch))[tn] = o;
    }
  }
}

// ---------------------------------------------------------------------------
// pack_all: one kernel, block-role dispatch (saves 3 launches + memset):
//  bx in [0,27)   : Bpack units (NH*2304 = 6912 = 27*256)
//  bx in {27,28}  : bcomb[h][n] = sum_k b_lin[k] W_heads[h][k][n]  (384)
//  bx == 29       : sbuf[o] = b_lin @ W_heads[h] @ att  (6 outputs)
//  bx >= 30       : zero counts[NN]  (196 blocks)
// ---------------------------------------------------------------------------
__global__ __launch_bounds__(256) void pack_all(const float* __restrict__ wcomb,
                                                const float* __restrict__ att_src,
                                                const float* __restrict__ att_dst,
                                                const float* __restrict__ b_lin,
                                                const float* __restrict__ W_heads,
                                                uint4* __restrict__ Bpack,
                                                float* __restrict__ bcomb,
                                                float* __restrict__ sbuf,
                                                int* __restrict__ counts) {
  const int bx = blockIdx.x;
  const int tid = threadIdx.x;
  if (bx < 27) {
    int u = bx * 256 + tid;            // < 6912 always
    int h = u / 2304, r = u % 2304;
    int nt = r >> 8, s = (r >> 6) & 3, q = (r >> 4) & 3, n0 = r & 15;
    int kbase = s * 32 + q * 8;
    float vals[8];
    if (nt < 8) {
      const float* W = wcomb + h * D * D + kbase * D + nt * 16 + n0;
      #pragma unroll
      for (int j = 0; j < 8; ++j) vals[j] = W[j * D];
    } else if (n0 < 2) {
      const float* a = (n0 ? att_dst : att_src) + h * D;
      const float* W = wcomb + h * D * D + kbase * D;
      #pragma unroll
      for (int j = 0; j < 8; ++j) {
        float acc = 0.f;
        for (int m = 0; m < D; ++m) acc += W[j * D + m] * a[m];
        vals[j] = acc;
      }
    } else {
      #pragma unroll
      for (int j = 0; j < 8; ++j) vals[j] = 0.f;
    }
    unsigned int w[4];
    #pragma unroll
    for (int p = 0; p < 4; ++p)
      w[p] = (unsigned int)f2b(vals[2 * p]) | ((unsigned int)f2b(vals[2 * p + 1]) << 16);
    Bpack[u] = make_uint4(w[0], w[1], w[2], w[3]);
  } else if (bx < 29) {
    int t = (bx - 27) * 256 + tid;
    if (t < NH * D) {
      int h = t / D, n = t - h * D;
      float acc = 0.f;
      for (int k = 0; k < D; ++k) acc += b_lin[k] * W_heads[h * D * D + k * D + n];
      bcomb[t] = acc;
    }
  } else if (bx == 29) {
    // sbuf[o], o = h*2 + (0:src,1:dst): threads 0..127 = k, LDS reduce
    __shared__ float red[128];
    for (int o = 0; o < 2 * NH; ++o) {
      int h = o >> 1;
      const float* a = (o & 1) ? (att_dst + h * D) : (att_src + h * D);
      float part = 0.f;
      if (tid < D) {
        const float* W = W_heads + h * D * D + tid * D;
        float acc = 0.f;
        for (int n = 0; n < D; ++n) acc += W[n] * a[n];
        part = b_lin[tid] * acc;
      }
      if (tid < D) red[tid] = part;
      __syncthreads();
      if (tid == 0) {
        float s = 0.f;
        for (int k = 0; k < D; ++k) s += red[k];
        sbuf[o] = s;
      }
      __syncthreads();
    }
  } else {
    int i = (bx - 30) * 256 + tid;
    if (i < NN) counts[i] = 0;
  }
}

// ---------------------------------------------------------------------------
// h3[n][head][d] (bf16) = x @ wcomb[head] + bcomb[head] via MFMA 16x16x32,
// PLUS s_src/s_dst score columns, PLUS the edge histogram (grid covers NE;
// one counts-atomic per thread, hidden under the MFMA work).
// ---------------------------------------------------------------------------
__global__ __launch_bounds__(256) void mfma_h3s(const float* __restrict__ x,
                                                const uint4* __restrict__ Bpack,
                                                const float* __restrict__ bcomb,
                                                const float* __restrict__ sbuf,
                                                const int* __restrict__ ei,
                                                int* __restrict__ counts,
                                                unsigned short* __restrict__ h3,
                                                float* __restrict__ s_src,
                                                float* __restrict__ s_dst) {
  const int head = blockIdx.y;
  const int row0 = blockIdx.x * 64;
  const int tid = threadIdx.x;
  // fused histogram: this grid has 782*3*256 = 600576 threads >= NE
  {
    int e = (blockIdx.y * gridDim.x + blockIdx.x) * 256 + tid;
    if (e < NE) atomicAdd(&counts[ei[NE + e]], 1);
  }
  __shared__ __align__(16) unsigned short As[64][136];
  #pragma unroll
  for (int it = 0; it < 8; ++it) {
    int idx = tid + it * 256;
    int m = idx >> 5, k4 = idx & 31;
    int row = row0 + m;
    float4 v = make_float4(0.f, 0.f, 0.f, 0.f);
    if (row < NN) v = ((const float4*)(x + (size_t)row * D))[k4];
    uint2 pk;
    pk.x = (unsigned int)f2b(v.x) | ((unsigned int)f2b(v.y) << 16);
    pk.y = (unsigned int)f2b(v.z) | ((unsigned int)f2b(v.w) << 16);
    *((uint2*)&As[m][k4 * 4]) = pk;
  }
  __syncthreads();
  const int wv = tid >> 6;
  const int lane = tid & 63;
  const int n0 = lane & 15, q = lane >> 4;
  const bf16x8* Bp = (const bf16x8*)(Bpack + head * 2304);

  f32x4 acc[9];
  #pragma unroll
  for (int nt = 0; nt < 9; ++nt) acc[nt] = (f32x4){0.f, 0.f, 0.f, 0.f};

  #pragma unroll
  for (int s = 0; s < 4; ++s) {
    bf16x8 a = *(const bf16x8*)&As[wv * 16 + n0][s * 32 + q * 8];
    #pragma unroll
    for (int nt = 0; nt < 9; ++nt) {
      bf16x8 b = Bp[(nt * 4 + s) * 64 + q * 16 + n0];
      acc[nt] = __builtin_amdgcn_mfma_f32_16x16x32_bf16(a, b, acc[nt], 0, 0, 0);
    }
  }
  const float* bc = bcomb + head * D;
  unsigned short* H = h3 + (size_t)head * D;
  #pragma unroll
  for (int nt = 0; nt < 8; ++nt) {
    int col = nt * 16 + n0;
    float bv = bc[col];
    #pragma unroll
    for (int r = 0; r < 4; ++r) {
      int row = row0 + wv * 16 + q * 4 + r;
      if (row < NN) H[(size_t)row * (NH * D) + col] = f2b(acc[nt][r] + bv);
    }
  }
  // score columns: n0==0 -> s_src, n0==1 -> s_dst  (C/D row = q*4+r)
  if (n0 < 2) {
    float sb = sbuf[head * 2 + n0];
    float* Sout = n0 ? s_dst : s_src;
    #pragma unroll
    for (int r = 0; r < 4; ++r) {
      int row = row0 + wv * 16 + q * 4 + r;
      if (row < NN) Sout[row * NH + head] = acc[8][r] + sb;
    }
  }
}

// --------------------------- CSR scan (2 launches) -------------------------
__global__ __launch_bounds__(256) void scan1(const int* __restrict__ counts,
                                             int* __restrict__ expart,
                                             int* __restrict__ blocksums) {
  __shared__ int tmp[2][256];
  int i = blockIdx.x * 256 + threadIdx.x;
  int t = threadIdx.x;
  int v = (i < NN) ? counts[i] : 0;
  tmp[0][t] = v;
  __syncthreads();
  int cur = 0;
  #pragma unroll
  for (int off = 1; off < 256; off <<= 1) {
    int nv = tmp[cur][t] + (t >= off ? tmp[cur][t - off] : 0);
    tmp[1 - cur][t] = nv;
    cur = 1 - cur;
    __syncthreads();
  }
  if (i < NN) expart[i] = tmp[cur][t] - v;
  if (t == 255) blocksums[blockIdx.x] = tmp[cur][t];
}

// scan3b: merged scan2+scan3 — each block reduces blocksums[0..bx) inline.
__global__ __launch_bounds__(256) void scan3b(const int* __restrict__ expart,
                                              const int* __restrict__ blocksums,
                                              int* __restrict__ row_start,
                                              int* __restrict__ cursor) {
  __shared__ int red[256];
  const int bx = blockIdx.x;
  const int t = threadIdx.x;
  red[t] = (t < bx) ? blocksums[t] : 0;    // bx <= 195 < 256
  __syncthreads();
  #pragma unroll
  for (int off = 128; off > 0; off >>= 1) {
    if (t < off) red[t] += red[t + off];
    __syncthreads();
  }
  int base = red[0];
  int i = bx * 256 + t;
  if (i < NN) {
    int v = expart[i] + base;
    row_start[i] = v;
    cursor[i] = v;
  }
  if (i == 0) row_start[NN] = NE;
}

// ---------------------------------------------------------------------------
// Scatter (proven): slots[slot] = {bitcast(src), p0, p1, p2}; ews stream.
// One int cursor atomic per edge only — NO float atomics.
// ---------------------------------------------------------------------------
__global__ __launch_bounds__(256) void scatter(const int* __restrict__ ei,
                                               const int* __restrict__ eid,
                                               const float* __restrict__ ddi,
                                               const float* __restrict__ emb,
                                               const float* __restrict__ s_src,
                                               const float* __restrict__ s_dst,
                                               int* __restrict__ cursor,
                                               float4* __restrict__ slots,
                                               float* __restrict__ ews) {
  int e = blockIdx.x * 256 + threadIdx.x;
  if (e >= NE) return;
  int src = ei[e], dst = ei[NE + e];
  int slot = atomicAdd(&cursor[dst], 1);
  float p[NH];
  #pragma unroll
  for (int hd = 0; hd < NH; ++hd) {
    float v = s_src[src * NH + hd] + s_dst[dst * NH + hd];
    v = v > 0.f ? v : 0.2f * v;
    p[hd] = __expf(v);   // no max-subtraction: |v| <= ~10, exp safe in fp32
  }
  slots[slot] = make_float4(__int_as_float(src), p[0], p[1], p[2]);
  ews[slot] = emb[eid[e]] - ddi[e];
}

// ---------------------------------------------------------------------------
// Gather v7: one wave per dst. Lanes 0-31 take even CSR slots, 32-63 odd;
// each half 2x unrolled -> 4 edges / 12 gather-loads in flight per lane.
// Lane covers 4 channels x 3 heads via uint2 loads. Halves combined via
// shfl_xor(32); lanes 0-31 write one coalesced float4. No atomics.
// ---------------------------------------------------------------------------
__global__ __launch_bounds__(64) void gather7(const int* __restrict__ row_start,
                                              const float4* __restrict__ slots,
                                              const float* __restrict__ ews,
                                              const unsigned short* __restrict__ h3,
                                              const float* __restrict__ bias_heads,
                                              float* __restrict__ out) {
  const int dst = blockIdx.x;
  const int lane = threadIdx.x;          // 0..63
  const int half = lane >> 5;
  const int c = (lane & 31) * 4;         // channel base (4 channels per lane)
  const int beg = row_start[dst], end = row_start[dst + 1];
  float a0[4] = {0.f, 0.f, 0.f, 0.f};
  float a1[4] = {0.f, 0.f, 0.f, 0.f};
  float a2[4] = {0.f, 0.f, 0.f, 0.f};
  float d0 = 0.f, d1 = 0.f, d2 = 0.f;
  int s = beg + half;
  for (; s + 2 < end; s += 4) {
    float4 A = slots[s];
    float4 B = slots[s + 2];
    float ewA = ews[s];
    float ewB = ews[s + 2];
    const unsigned short* ha = h3 + (size_t)__float_as_int(A.x) * (NH * D);
    const unsigned short* hb = h3 + (size_t)__float_as_int(B.x) * (NH * D);
    uint2 ua0 = *(const uint2*)&ha[c];
    uint2 ua1 = *(const uint2*)&ha[D + c];
    uint2 ua2 = *(const uint2*)&ha[2 * D + c];
    uint2 ub0 = *(const uint2*)&hb[c];
    uint2 ub1 = *(const uint2*)&hb[D + c];
    uint2 ub2 = *(const uint2*)&hb[2 * D + c];
    float wa0 = A.y * ewA, wa1 = A.z * ewA, wa2 = A.w * ewA;
    float wb0 = B.y * ewB, wb1 = B.z * ewB, wb2 = B.w * ewB;
    a0[0] += wa0 * blo(ua0.x) + wb0 * blo(ub0.x);
    a0[1] += wa0 * bhi(ua0.x) + wb0 * bhi(ub0.x);
    a0[2] += wa0 * blo(ua0.y) + wb0 * blo(ub0.y);
    a0[3] += wa0 * bhi(ua0.y) + wb0 * bhi(ub0.y);
    a1[0] += wa1 * blo(ua1.x) + wb1 * blo(ub1.x);
    a1[1] += wa1 * bhi(ua1.x) + wb1 * bhi(ub1.x);
    a1[2] += wa1 * blo(ua1.y) + wb1 * blo(ub1.y);
    a1[3] += wa1 * bhi(ua1.y) + wb1 * bhi(ub1.y);
    a2[0] += wa2 * blo(ua2.x) + wb2 * blo(ub2.x);
    a2[1] += wa2 * bhi(ua2.x) + wb2 * bhi(ub2.x);
    a2[2] += wa2 * blo(ua2.y) + wb2 * blo(ub2.y);
    a2[3] += wa2 * bhi(ua2.y) + wb2 * bhi(ub2.y);
    d0 += A.y + B.y;
    d1 += A.z + B.z;
    d2 += A.w + B.w;
  }
  if (s < end) {
    float4 A = slots[s];
    float ew = ews[s];
    const unsigned short* hp = h3 + (size_t)__float_as_int(A.x) * (NH * D);
    uint2 u0 = *(const uint2*)&hp[c];
    uint2 u1 = *(const uint2*)&hp[D + c];
    uint2 u2 = *(const uint2*)&hp[2 * D + c];
    float w0 = A.y * ew, w1 = A.z * ew, w2 = A.w * ew;
    a0[0] += w0 * blo(u0.x); a0[1] += w0 * bhi(u0.x);
    a0[2] += w0 * blo(u0.y); a0[3] += w0 * bhi(u0.y);
    a1[0] += w1 * blo(u1.x); a1[1] += w1 * bhi(u1.x);
    a1[2] += w1 * blo(u1.y); a1[3] += w1 * bhi(u1.y);
    a2[0] += w2 * blo(u2.x); a2[1] += w2 * bhi(u2.x);
    a2[2] += w2 * blo(u2.y); a2[3] += w2 * bhi(u2.y);
    d0 += A.y; d1 += A.z; d2 += A.w;
  }
  // combine the two half-wave edge streams
  #pragma unroll
  for (int j = 0; j < 4; ++j) {
    a0[j] += __shfl_xor(a0[j], 32, 64);
    a1[j] += __shfl_xor(a1[j], 32, 64);
    a2[j] += __shfl_xor(a2[j], 32, 64);
  }
  d0 += __shfl_xor(d0, 32, 64);
  d1 += __shfl_xor(d1, 32, 64);
  d2 += __shfl_xor(d2, 32, 64);
  if (half == 0) {
    float r0 = 1.f / fmaxf(d0, 1e-16f);
    float r1 = 1.f / fmaxf(d1, 1e-16f);
    float r2 = 1.f / fmaxf(d2, 1e-16f);
    float4 b0 = ((const float4*)bias_heads)[lane & 31];
    float4 b1 = ((const float4*)bias_heads)[32 + (lane & 31)];
    float4 b2 = ((const float4*)bias_heads)[64 + (lane & 31)];
    float4 o;
    o.x = (a0[0] * r0 + a1[0] * r1 + a2[0] * r2 + b0.x + b1.x + b2.x) * (1.f / 3.f);
    o.y = (a0[1] * r0 + a1[1] * r1 + a2[1] * r2 + b0.y + b1.y + b2.y) * (1.f / 3.f);
    o.z = (a0[2] * r0 + a1[2] * r1 + a2[2] * r2 + b0.z + b1.z + b2.z) * (1.f / 3.f);
    o.w = (a0[3] * r0 + a1[3] * r1 + a2[3] * r2 + b0.w + b1.w + b2.w) * (1.f / 3.f);
    *((float4*)&out[(size_t)dst * D + c]) = o;
  }
}

// ---------------------------------------------------------------------------
extern "C" void kernel_launch(void* const* d_in, const int* in_sizes, int n_in,
                              void* d_out, int out_size, void* d_ws, size_t ws_size,
                              hipStream_t stream) {
  const float* x          = (const float*)d_in[0];
  const int*   ei         = (const int*)d_in[1];
  const int*   eid        = (const int*)d_in[2];
  const float* ddi        = (const float*)d_in[3];
  const float* W_lin      = (const float*)d_in[4];
  const float* b_lin      = (const float*)d_in[5];
  const float* emb        = (const float*)d_in[6];
  const float* W_heads    = (const float*)d_in[7];
  const float* att_src    = (const float*)d_in[8];
  const float* att_dst    = (const float*)d_in[9];
  const float* bias_heads = (const float*)d_in[10];
  float* out = (float*)d_out;

  // workspace layout (16B-aligned chunks first)
  float4* slots  = (float4*)d_ws;                              // NE
  uint4*  Bpack  = (uint4*)(slots + NE);                       // NH*2304
  unsigned short* h3 = (unsigned short*)(Bpack + NH * 2304);   // NN*NH*D bf16
  float*  wcomb  = (float*)(h3 + (size_t)NN * NH * D);         // NH*D*D
  float*  ews    = wcomb + NH * D * D;                         // NE
  float*  bcomb  = ews + NE;                                   // NH*D
  float*  sbuf   = bcomb + NH * D;                             // 8
  float*  s_src  = sbuf + 8;                                   // NN*NH
  float*  s_dst  = s_src + NN * NH;                            // NN*NH
  int*    counts = (int*)(s_dst + NN * NH);                    // NN (zeroed in pack_all)
  int*    expart = counts + NN;                                // NN
  int*    bsums  = expart + NN;                                // 256
  int*    rstart = bsums + 256;                                // NN+1
  int*    cursor = rstart + NN + 1;                            // NN

  const int edgeBlocks = (NE + 255) / 256;

  // 1. wcomb[h] = W_lin @ W_heads[h]
  gemm128<<<dim3(2, NH), 256, 0, stream>>>(W_lin, W_heads, nullptr, wcomb, D,
                                           (size_t)D * D, (size_t)D * D, D);
  // 2. pack Bpack + bcomb + sbuf + zero counts (one kernel, 226 blocks)
  pack_all<<<30 + SCAN_BLOCKS, 256, 0, stream>>>(wcomb, att_src, att_dst, b_lin,
                                                 W_heads, Bpack, bcomb, sbuf, counts);
  // 3. h3 + scores + edge histogram in one MFMA pass
  mfma_h3s<<<dim3((NN + 63) / 64, NH), 256, 0, stream>>>(x, Bpack, bcomb, sbuf,
                                                         ei, counts, h3, s_src, s_dst);
  // 4. CSR scan (2 launches)
  scan1<<<SCAN_BLOCKS, 256, 0, stream>>>(counts, expart, bsums);
  scan3b<<<SCAN_BLOCKS, 256, 0, stream>>>(expart, bsums, rstart, cursor);
  // 5. scatter edges into CSR (int cursor atomic only)
  scatter<<<edgeBlocks, 256, 0, stream>>>(ei, eid, ddi, emb, s_src, s_dst, cursor,
                                          slots, ews);
  // 6. per-dst gather: 1 wave/dst, 4 edges in flight, no atomics
  gather7<<<NN, 64, 0, stream>>>(rstart, slots, ews, h3, bias_heads, out);
}

// Round 11
// 263.009 us; speedup vs baseline: 1.6177x; 1.1300x over previous
//
#include <hip/hip_runtime.h>
#include <math.h>

#define NN 50000
#define NE 600000
#define D 128
#define NH 3
#define SCAN_BLOCKS ((NN + 255) / 256)   // 196

typedef short bf16x8 __attribute__((ext_vector_type(8)));
typedef float f32x4 __attribute__((ext_vector_type(4)));

__device__ __forceinline__ unsigned short f2b(float f) {
  unsigned int u = __float_as_uint(f);
  u += 0x7FFF + ((u >> 16) & 1);          // round-to-nearest-even
  return (unsigned short)(u >> 16);
}
__device__ __forceinline__ float blo(unsigned int u) {
  return __uint_as_float(u << 16);
}
__device__ __forceinline__ float bhi(unsigned int u) {
  return __uint_as_float(u & 0xffff0000u);
}

// ---------------------------------------------------------------------------
// pack_all: one kernel, block-role dispatch. No wcomb intermediate — Bpack
// computed straight from W_lin/W_heads (wcomb[k][n] = sum_m Wl[k][m] Wh[m][n]).
//  bx in [0,24)  : Bpack nt<8 units (NH*2048 = 6144 = 24*256)
//  bx in [24,27) : per-head score columns (nt==8) via LDS 2-stage + sbuf
//  bx in {27,28} : bcomb[h][n] = sum_k b_lin[k] W_heads[h][k][n]  (384)
//  bx >= 29      : zero counts[NN]  (196 blocks)
// ---------------------------------------------------------------------------
__global__ __launch_bounds__(256) void pack_all(const float* __restrict__ W_lin,
                                                const float* __restrict__ W_heads,
                                                const float* __restrict__ att_src,
                                                const float* __restrict__ att_dst,
                                                const float* __restrict__ b_lin,
                                                uint4* __restrict__ Bpack,
                                                float* __restrict__ bcomb,
                                                float* __restrict__ sbuf,
                                                int* __restrict__ counts) {
  const int bx = blockIdx.x;
  const int tid = threadIdx.x;
  if (bx < 24) {
    // Bpack unit: 8 bf16 { wcomb[k=kbase+j][n] } , wcomb = W_lin @ W_heads[h]
    int u = bx * 256 + tid;            // < 6144
    int h = u >> 11, r = u & 2047;
    int nt = r >> 8, s = (r >> 6) & 3, q = (r >> 4) & 3, n0 = r & 15;
    int kbase = s * 32 + q * 8;
    int n = nt * 16 + n0;
    const float* wl = W_lin + kbase * D;
    const float* wh = W_heads + h * D * D + n;
    float vals[8];
    #pragma unroll
    for (int j = 0; j < 8; ++j) vals[j] = 0.f;
    for (int m = 0; m < D; ++m) {
      float whv = wh[m * D];
      #pragma unroll
      for (int j = 0; j < 8; ++j) vals[j] += wl[j * D + m] * whv;
    }
    unsigned int w[4];
    #pragma unroll
    for (int p = 0; p < 4; ++p)
      w[p] = (unsigned int)f2b(vals[2 * p]) | ((unsigned int)f2b(vals[2 * p + 1]) << 16);
    Bpack[h * 2304 + r] = make_uint4(w[0], w[1], w[2], w[3]);
  } else if (bx < 27) {
    // score columns for head h: sc[k] = sum_m W_lin[k][m] * wha[m],
    // wha[m] = sum_n W_heads[h][m][n] * att[n]. Also sbuf = b_lin . wha.
    const int h = bx - 24;
    __shared__ float wha_s[128], wha_d[128], scs[128], scd[128];
    {
      int m = tid & 127;
      const float* W = W_heads + h * D * D + m * D;
      const float* a = (tid < 128) ? (att_src + h * D) : (att_dst + h * D);
      float acc = 0.f;
      for (int n = 0; n < D; ++n) acc += W[n] * a[n];
      if (tid < 128) wha_s[m] = acc; else wha_d[m] = acc;
    }
    __syncthreads();
    {
      int k = tid & 127;
      const float* wl = W_lin + k * D;
      const float* wha = (tid < 128) ? wha_s : wha_d;
      float acc = 0.f;
      for (int m = 0; m < D; ++m) acc += wl[m] * wha[m];
      if (tid < 128) scs[k] = acc; else scd[k] = acc;
    }
    __syncthreads();
    if (tid < 2) {
      const float* wha = tid ? wha_d : wha_s;
      float a = 0.f;
      for (int k = 0; k < D; ++k) a += b_lin[k] * wha[k];
      sbuf[h * 2 + tid] = a;
    }
    // write the 256 nt==8 units for this head
    {
      int s = (tid >> 6) & 3, q = (tid >> 4) & 3, n0 = tid & 15;
      int kbase = s * 32 + q * 8;
      float vals[8];
      #pragma unroll
      for (int j = 0; j < 8; ++j)
        vals[j] = (n0 == 0) ? scs[kbase + j] : ((n0 == 1) ? scd[kbase + j] : 0.f);
      unsigned int w[4];
      #pragma unroll
      for (int p = 0; p < 4; ++p)
        w[p] = (unsigned int)f2b(vals[2 * p]) | ((unsigned int)f2b(vals[2 * p + 1]) << 16);
      Bpack[h * 2304 + 2048 + tid] = make_uint4(w[0], w[1], w[2], w[3]);
    }
  } else if (bx < 29) {
    int t = (bx - 27) * 256 + tid;
    if (t < NH * D) {
      int h = t / D, n = t - h * D;
      float acc = 0.f;
      for (int k = 0; k < D; ++k) acc += b_lin[k] * W_heads[h * D * D + k * D + n];
      bcomb[t] = acc;
    }
  } else {
    int i = (bx - 29) * 256 + tid;
    if (i < NN) counts[i] = 0;
  }
}

// ---------------------------------------------------------------------------
// h3[n][head][d] (bf16) = x @ wcomb[head] + bcomb[head] via MFMA 16x16x32,
// PLUS s_src/s_dst score columns, PLUS the edge histogram (grid covers NE).
// ---------------------------------------------------------------------------
__global__ __launch_bounds__(256) void mfma_h3s(const float* __restrict__ x,
                                                const uint4* __restrict__ Bpack,
                                                const float* __restrict__ bcomb,
                                                const float* __restrict__ sbuf,
                                                const int* __restrict__ ei,
                                                int* __restrict__ counts,
                                                unsigned short* __restrict__ h3,
                                                float* __restrict__ s_src,
                                                float* __restrict__ s_dst) {
  const int head = blockIdx.y;
  const int row0 = blockIdx.x * 64;
  const int tid = threadIdx.x;
  // fused histogram: this grid has 782*3*256 = 600576 threads >= NE
  {
    int e = (blockIdx.y * gridDim.x + blockIdx.x) * 256 + tid;
    if (e < NE) atomicAdd(&counts[ei[NE + e]], 1);
  }
  __shared__ __align__(16) unsigned short As[64][136];
  #pragma unroll
  for (int it = 0; it < 8; ++it) {
    int idx = tid + it * 256;
    int m = idx >> 5, k4 = idx & 31;
    int row = row0 + m;
    float4 v = make_float4(0.f, 0.f, 0.f, 0.f);
    if (row < NN) v = ((const float4*)(x + (size_t)row * D))[k4];
    uint2 pk;
    pk.x = (unsigned int)f2b(v.x) | ((unsigned int)f2b(v.y) << 16);
    pk.y = (unsigned int)f2b(v.z) | ((unsigned int)f2b(v.w) << 16);
    *((uint2*)&As[m][k4 * 4]) = pk;
  }
  __syncthreads();
  const int wv = tid >> 6;
  const int lane = tid & 63;
  const int n0 = lane & 15, q = lane >> 4;
  const bf16x8* Bp = (const bf16x8*)(Bpack + head * 2304);

  f32x4 acc[9];
  #pragma unroll
  for (int nt = 0; nt < 9; ++nt) acc[nt] = (f32x4){0.f, 0.f, 0.f, 0.f};

  #pragma unroll
  for (int s = 0; s < 4; ++s) {
    bf16x8 a = *(const bf16x8*)&As[wv * 16 + n0][s * 32 + q * 8];
    #pragma unroll
    for (int nt = 0; nt < 9; ++nt) {
      bf16x8 b = Bp[(nt * 4 + s) * 64 + q * 16 + n0];
      acc[nt] = __builtin_amdgcn_mfma_f32_16x16x32_bf16(a, b, acc[nt], 0, 0, 0);
    }
  }
  const float* bc = bcomb + head * D;
  unsigned short* H = h3 + (size_t)head * D;
  #pragma unroll
  for (int nt = 0; nt < 8; ++nt) {
    int col = nt * 16 + n0;
    float bv = bc[col];
    #pragma unroll
    for (int r = 0; r < 4; ++r) {
      int row = row0 + wv * 16 + q * 4 + r;
      if (row < NN) H[(size_t)row * (NH * D) + col] = f2b(acc[nt][r] + bv);
    }
  }
  // score columns: n0==0 -> s_src, n0==1 -> s_dst  (C/D row = q*4+r)
  if (n0 < 2) {
    float sb = sbuf[head * 2 + n0];
    float* Sout = n0 ? s_dst : s_src;
    #pragma unroll
    for (int r = 0; r < 4; ++r) {
      int row = row0 + wv * 16 + q * 4 + r;
      if (row < NN) Sout[row * NH + head] = acc[8][r] + sb;
    }
  }
}

// --------------------------- CSR scan (2 launches) -------------------------
__global__ __launch_bounds__(256) void scan1(const int* __restrict__ counts,
                                             int* __restrict__ expart,
                                             int* __restrict__ blocksums) {
  __shared__ int tmp[2][256];
  int i = blockIdx.x * 256 + threadIdx.x;
  int t = threadIdx.x;
  int v = (i < NN) ? counts[i] : 0;
  tmp[0][t] = v;
  __syncthreads();
  int cur = 0;
  #pragma unroll
  for (int off = 1; off < 256; off <<= 1) {
    int nv = tmp[cur][t] + (t >= off ? tmp[cur][t - off] : 0);
    tmp[1 - cur][t] = nv;
    cur = 1 - cur;
    __syncthreads();
  }
  if (i < NN) expart[i] = tmp[cur][t] - v;
  if (t == 255) blocksums[blockIdx.x] = tmp[cur][t];
}

// scan3b: merged scan2+scan3 — each block reduces blocksums[0..bx) inline.
__global__ __launch_bounds__(256) void scan3b(const int* __restrict__ expart,
                                              const int* __restrict__ blocksums,
                                              int* __restrict__ row_start,
                                              int* __restrict__ cursor) {
  __shared__ int red[256];
  const int bx = blockIdx.x;
  const int t = threadIdx.x;
  red[t] = (t < bx) ? blocksums[t] : 0;    // bx <= 195 < 256
  __syncthreads();
  #pragma unroll
  for (int off = 128; off > 0; off >>= 1) {
    if (t < off) red[t] += red[t + off];
    __syncthreads();
  }
  int base = red[0];
  int i = bx * 256 + t;
  if (i < NN) {
    int v = expart[i] + base;
    row_start[i] = v;
    cursor[i] = v;
  }
  if (i == 0) row_start[NN] = NE;
}

// ---------------------------------------------------------------------------
// Scatter: slots[slot] = { src(16b) | ew_bf16(16b), p0, p1, p2 }.
// One int cursor atomic per edge only — NO float atomics, no ews array.
// ---------------------------------------------------------------------------
__global__ __launch_bounds__(256) void scatter(const int* __restrict__ ei,
                                               const int* __restrict__ eid,
                                               const float* __restrict__ ddi,
                                               const float* __restrict__ emb,
                                               const float* __restrict__ s_src,
                                               const float* __restrict__ s_dst,
                                               int* __restrict__ cursor,
                                               float4* __restrict__ slots) {
  int e = blockIdx.x * 256 + threadIdx.x;
  if (e >= NE) return;
  int src = ei[e], dst = ei[NE + e];
  int slot = atomicAdd(&cursor[dst], 1);
  float ew = emb[eid[e]] - ddi[e];
  float p[NH];
  #pragma unroll
  for (int hd = 0; hd < NH; ++hd) {
    float v = s_src[src * NH + hd] + s_dst[dst * NH + hd];
    v = v > 0.f ? v : 0.2f * v;
    p[hd] = __expf(v);   // no max-subtraction: |v| <= ~10, exp safe in fp32
  }
  unsigned int se = (unsigned int)src | ((unsigned int)f2b(ew) << 16);
  slots[slot] = make_float4(__uint_as_float(se), p[0], p[1], p[2]);
}

// ---------------------------------------------------------------------------
// Gather v8: one wave per dst. Lanes 0-31 take even CSR slots, 32-63 odd;
// each half 2x unrolled -> 4 edges / 12 gather-loads in flight per lane.
// src+ew unpacked from slots.x (src low 16 bits, ew bf16 high 16 bits).
// Halves combined via shfl_xor(32); lanes 0-31 write one float4. No atomics.
// ---------------------------------------------------------------------------
__global__ __launch_bounds__(64) void gather8(const int* __restrict__ row_start,
                                              const float4* __restrict__ slots,
                                              const unsigned short* __restrict__ h3,
                                              const float* __restrict__ bias_heads,
                                              float* __restrict__ out) {
  const int dst = blockIdx.x;
  const int lane = threadIdx.x;          // 0..63
  const int half = lane >> 5;
  const int c = (lane & 31) * 4;         // channel base (4 channels per lane)
  const int beg = row_start[dst], end = row_start[dst + 1];
  float a0[4] = {0.f, 0.f, 0.f, 0.f};
  float a1[4] = {0.f, 0.f, 0.f, 0.f};
  float a2[4] = {0.f, 0.f, 0.f, 0.f};
  float d0 = 0.f, d1 = 0.f, d2 = 0.f;
  int s = beg + half;
  for (; s + 2 < end; s += 4) {
    float4 A = slots[s];
    float4 B = slots[s + 2];
    unsigned int seA = __float_as_uint(A.x);
    unsigned int seB = __float_as_uint(B.x);
    const unsigned short* ha = h3 + (size_t)(seA & 0xffffu) * (NH * D);
    const unsigned short* hb = h3 + (size_t)(seB & 0xffffu) * (NH * D);
    float ewA = bhi(seA), ewB = bhi(seB);
    uint2 ua0 = *(const uint2*)&ha[c];
    uint2 ua1 = *(const uint2*)&ha[D + c];
    uint2 ua2 = *(const uint2*)&ha[2 * D + c];
    uint2 ub0 = *(const uint2*)&hb[c];
    uint2 ub1 = *(const uint2*)&hb[D + c];
    uint2 ub2 = *(const uint2*)&hb[2 * D + c];
    float wa0 = A.y * ewA, wa1 = A.z * ewA, wa2 = A.w * ewA;
    float wb0 = B.y * ewB, wb1 = B.z * ewB, wb2 = B.w * ewB;
    a0[0] += wa0 * blo(ua0.x) + wb0 * blo(ub0.x);
    a0[1] += wa0 * bhi(ua0.x) + wb0 * bhi(ub0.x);
    a0[2] += wa0 * blo(ua0.y) + wb0 * blo(ub0.y);
    a0[3] += wa0 * bhi(ua0.y) + wb0 * bhi(ub0.y);
    a1[0] += wa1 * blo(ua1.x) + wb1 * blo(ub1.x);
    a1[1] += wa1 * bhi(ua1.x) + wb1 * bhi(ub1.x);
    a1[2] += wa1 * blo(ua1.y) + wb1 * blo(ub1.y);
    a1[3] += wa1 * bhi(ua1.y) + wb1 * bhi(ub1.y);
    a2[0] += wa2 * blo(ua2.x) + wb2 * blo(ub2.x);
    a2[1] += wa2 * bhi(ua2.x) + wb2 * bhi(ub2.x);
    a2[2] += wa2 * blo(ua2.y) + wb2 * blo(ub2.y);
    a2[3] += wa2 * bhi(ua2.y) + wb2 * bhi(ub2.y);
    d0 += A.y + B.y;
    d1 += A.z + B.z;
    d2 += A.w + B.w;
  }
  if (s < end) {
    float4 A = slots[s];
    unsigned int seA = __float_as_uint(A.x);
    const unsigned short* hp = h3 + (size_t)(seA & 0xffffu) * (NH * D);
    float ew = bhi(seA);
    uint2 u0 = *(const uint2*)&hp[c];
    uint2 u1 = *(const uint2*)&hp[D + c];
    uint2 u2 = *(const uint2*)&hp[2 * D + c];
    float w0 = A.y * ew, w1 = A.z * ew, w2 = A.w * ew;
    a0[0] += w0 * blo(u0.x); a0[1] += w0 * bhi(u0.x);
    a0[2] += w0 * blo(u0.y); a0[3] += w0 * bhi(u0.y);
    a1[0] += w1 * blo(u1.x); a1[1] += w1 * bhi(u1.x);
    a1[2] += w1 * blo(u1.y); a1[3] += w1 * bhi(u1.y);
    a2[0] += w2 * blo(u2.x); a2[1] += w2 * bhi(u2.x);
    a2[2] += w2 * blo(u2.y); a2[3] += w2 * bhi(u2.y);
    d0 += A.y; d1 += A.z; d2 += A.w;
  }
  // combine the two half-wave edge streams
  #pragma unroll
  for (int j = 0; j < 4; ++j) {
    a0[j] += __shfl_xor(a0[j], 32, 64);
    a1[j] += __shfl_xor(a1[j], 32, 64);
    a2[j] += __shfl_xor(a2[j], 32, 64);
  }
  d0 += __shfl_xor(d0, 32, 64);
  d1 += __shfl_xor(d1, 32, 64);
  d2 += __shfl_xor(d2, 32, 64);
  if (half == 0) {
    float r0 = 1.f / fmaxf(d0, 1e-16f);
    float r1 = 1.f / fmaxf(d1, 1e-16f);
    float r2 = 1.f / fmaxf(d2, 1e-16f);
    float4 b0 = ((const float4*)bias_heads)[lane & 31];
    float4 b1 = ((const float4*)bias_heads)[32 + (lane & 31)];
    float4 b2 = ((const float4*)bias_heads)[64 + (lane & 31)];
    float4 o;
    o.x = (a0[0] * r0 + a1[0] * r1 + a2[0] * r2 + b0.x + b1.x + b2.x) * (1.f / 3.f);
    o.y = (a0[1] * r0 + a1[1] * r1 + a2[1] * r2 + b0.y + b1.y + b2.y) * (1.f / 3.f);
    o.z = (a0[2] * r0 + a1[2] * r1 + a2[2] * r2 + b0.z + b1.z + b2.z) * (1.f / 3.f);
    o.w = (a0[3] * r0 + a1[3] * r1 + a2[3] * r2 + b0.w + b1.w + b2.w) * (1.f / 3.f);
    *((float4*)&out[(size_t)dst * D + c]) = o;
  }
}

// ---------------------------------------------------------------------------
extern "C" void kernel_launch(void* const* d_in, const int* in_sizes, int n_in,
                              void* d_out, int out_size, void* d_ws, size_t ws_size,
                              hipStream_t stream) {
  const float* x          = (const float*)d_in[0];
  const int*   ei         = (const int*)d_in[1];
  const int*   eid        = (const int*)d_in[2];
  const float* ddi        = (const float*)d_in[3];
  const float* W_lin      = (const float*)d_in[4];
  const float* b_lin      = (const float*)d_in[5];
  const float* emb        = (const float*)d_in[6];
  const float* W_heads    = (const float*)d_in[7];
  const float* att_src    = (const float*)d_in[8];
  const float* att_dst    = (const float*)d_in[9];
  const float* bias_heads = (const float*)d_in[10];
  float* out = (float*)d_out;

  // workspace layout (16B-aligned chunks first)
  float4* slots  = (float4*)d_ws;                              // NE
  uint4*  Bpack  = (uint4*)(slots + NE);                       // NH*2304
  unsigned short* h3 = (unsigned short*)(Bpack + NH * 2304);   // NN*NH*D bf16
  float*  bcomb  = (float*)(h3 + (size_t)NN * NH * D);         // NH*D
  float*  sbuf   = bcomb + NH * D;                             // 8
  float*  s_src  = sbuf + 8;                                   // NN*NH
  float*  s_dst  = s_src + NN * NH;                            // NN*NH
  int*    counts = (int*)(s_dst + NN * NH);                    // NN (zeroed in pack_all)
  int*    expart = counts + NN;                                // NN
  int*    bsums  = expart + NN;                                // 256
  int*    rstart = bsums + 256;                                // NN+1
  int*    cursor = rstart + NN + 1;                            // NN

  const int edgeBlocks = (NE + 255) / 256;

  // 1. Bpack (direct from W_lin/W_heads) + score cols + bcomb + sbuf + zero counts
  pack_all<<<29 + SCAN_BLOCKS, 256, 0, stream>>>(W_lin, W_heads, att_src, att_dst,
                                                 b_lin, Bpack, bcomb, sbuf, counts);
  // 2. h3 + scores + edge histogram in one MFMA pass
  mfma_h3s<<<dim3((NN + 63) / 64, NH), 256, 0, stream>>>(x, Bpack, bcomb, sbuf,
                                                         ei, counts, h3, s_src, s_dst);
  // 3. CSR scan (2 launches)
  scan1<<<SCAN_BLOCKS, 256, 0, stream>>>(counts, expart, bsums);
  scan3b<<<SCAN_BLOCKS, 256, 0, stream>>>(expart, bsums, rstart, cursor);
  // 4. scatter edges into CSR (int cursor atomic only; src+ew packed)
  scatter<<<edgeBlocks, 256, 0, stream>>>(ei, eid, ddi, emb, s_src, s_dst, cursor,
                                          slots);
  // 5. per-dst gather: 1 wave/dst, 4 edges in flight, no atomics
  gather8<<<NN, 64, 0, stream>>>(rstart, slots, h3, bias_heads, out);
}